// Round 1
// baseline (43520.020 us; speedup 1.0000x reference)
//
#include <hip/hip_runtime.h>
#include <hip/hip_bf16.h>
#include <math.h>

#define HH 384
#define WW 384
#define HW (HH*WW)
#define BB 4
#define CC 8
#define NLAYERS 5
#define CGITERS 10
#define PI_F 3.14159265358979323846f

struct cf { float x, y; };
__device__ __forceinline__ cf cadd(cf a, cf b){ cf r; r.x=a.x+b.x; r.y=a.y+b.y; return r; }
__device__ __forceinline__ cf csub(cf a, cf b){ cf r; r.x=a.x-b.x; r.y=a.y-b.y; return r; }
__device__ __forceinline__ cf cmul(cf a, cf b){ cf r; r.x=a.x*b.x - a.y*b.y; r.y=a.x*b.y + a.y*b.x; return r; }
__device__ __forceinline__ cf shflxor(cf v, int m){ cf r; r.x = __shfl_xor(v.x, m); r.y = __shfl_xor(v.y, m); return r; }
__device__ __forceinline__ int brev7(int l){ return (int)(__brev((unsigned)l) >> 25); }

__device__ __forceinline__ void radix3(cf a0, cf a1, cf a2, float s3, cf y[3]) {
  float tx = a1.x + a2.x, ty_ = a1.y + a2.y;
  float ux = a1.x - a2.x, uy = a1.y - a2.y;
  y[0].x = a0.x + tx;              y[0].y = a0.y + ty_;
  y[1].x = a0.x - 0.5f*tx - s3*uy; y[1].y = a0.y - 0.5f*ty_ + s3*ux;
  y[2].x = a0.x - 0.5f*tx + s3*uy; y[2].y = a0.y - 0.5f*ty_ - s3*ux;
}

// 384-point DFT across one 64-lane wave. SIGN=-1 fwd, +1 inverse (no 1/N scale).
// Input: v[m] = x[l + 64*m] (natural order).
// Output: uA[k1] = X[k1 + 3*rev7(l)], uB[k1] = X[k1 + 3*(rev7(l)+1)].
template<int SIGN>
__device__ __forceinline__ void fft384_wave(int l, const cf v[6], cf uA[3], cf uB[3]) {
  const float s3 = SIGN * 0.8660254037844386f;
  radix3(v[0], v[2], v[4], s3, uA);   // n2 = l
  radix3(v[1], v[3], v[5], s3, uB);   // n2 = l + 64
  const float base = SIGN * (2.0f * PI_F / 384.0f);
  float sA, cA; __sincosf(base * (float)l, &sA, &cA);
  cf wA1; wA1.x = cA; wA1.y = sA; cf wA2 = cmul(wA1, wA1);
  float sB, cB; __sincosf(base * (float)(l + 64), &sB, &cB);
  cf wB1; wB1.x = cB; wB1.y = sB; cf wB2 = cmul(wB1, wB1);
  uA[1] = cmul(uA[1], wA1); uA[2] = cmul(uA[2], wA2);
  uB[1] = cmul(uB[1], wB1); uB[2] = cmul(uB[2], wB2);
  // 128-pt DIF, stage h=64: pair (l, l+64) is thread-local
  {
    float s, c; __sincosf(SIGN * (PI_F/64.0f) * (float)l, &s, &c);
    cf w; w.x = c; w.y = s;
    #pragma unroll
    for (int k1 = 0; k1 < 3; ++k1) {
      cf a = uA[k1], b = uB[k1];
      uA[k1] = cadd(a, b);
      uB[k1] = cmul(csub(a, b), w);
    }
  }
  // stages h=32..1 via shfl_xor within the wave
  #pragma unroll
  for (int h = 32; h >= 1; h >>= 1) {
    const int j = l & (h - 1);
    float s, c; __sincosf(SIGN * PI_F * (float)j / (float)h, &s, &c);
    cf w; w.x = c; w.y = s;
    const bool up = (l & h) != 0;
    #pragma unroll
    for (int k1 = 0; k1 < 3; ++k1) {
      cf pa = shflxor(uA[k1], h);
      cf pb = shflxor(uB[k1], h);
      cf na = up ? cmul(csub(pa, uA[k1]), w) : cadd(uA[k1], pa);
      cf nb = up ? cmul(csub(pb, uB[k1]), w) : cadd(uB[k1], pb);
      uA[k1] = na; uB[k1] = nb;
    }
  }
}

// ---------------- conv kernels ----------------
// tile: 32x8 outputs per block, one thread per pixel, all couts in registers.

__global__ void __launch_bounds__(256) conv_in_k(const float* __restrict__ xin,
                                                 const float* __restrict__ w,
                                                 const float* __restrict__ bias,
                                                 __hip_bfloat16* __restrict__ out) {
  __shared__ float tile[2][340];
  const int tx = threadIdx.x & 31, ty = threadIdx.x >> 5;
  const int x0 = blockIdx.x * 32, y0 = blockIdx.y * 8, b = blockIdx.z;
  for (int e = threadIdx.x; e < 680; e += 256) {
    int ci = e / 340, rr = e % 340;
    int iy = y0 - 1 + rr / 34, ix = x0 - 1 + rr % 34;
    float v = 0.f;
    if (iy >= 0 && iy < HH && ix >= 0 && ix < WW)
      v = xin[(b*2 + ci)*HW + iy*WW + ix];
    tile[ci][rr] = v;
  }
  __syncthreads();
  float acc[64];
  #pragma unroll
  for (int co = 0; co < 64; ++co) acc[co] = bias[co];
  #pragma unroll
  for (int ci = 0; ci < 2; ++ci) {
    float v0 = tile[ci][ty*34+tx],     v1 = tile[ci][ty*34+tx+1],     v2 = tile[ci][ty*34+tx+2];
    float v3 = tile[ci][(ty+1)*34+tx], v4 = tile[ci][(ty+1)*34+tx+1], v5 = tile[ci][(ty+1)*34+tx+2];
    float v6 = tile[ci][(ty+2)*34+tx], v7 = tile[ci][(ty+2)*34+tx+1], v8 = tile[ci][(ty+2)*34+tx+2];
    #pragma unroll
    for (int co = 0; co < 64; ++co) {
      const float* wp = w + co*18 + ci*9;
      float a = acc[co];
      a = fmaf(v0, wp[0], a); a = fmaf(v1, wp[1], a); a = fmaf(v2, wp[2], a);
      a = fmaf(v3, wp[3], a); a = fmaf(v4, wp[4], a); a = fmaf(v5, wp[5], a);
      a = fmaf(v6, wp[6], a); a = fmaf(v7, wp[7], a); a = fmaf(v8, wp[8], a);
      acc[co] = a;
    }
  }
  const int oidx = (y0+ty)*WW + (x0+tx);
  #pragma unroll
  for (int co = 0; co < 64; ++co)
    out[(b*64+co)*HW + oidx] = __float2bfloat16(acc[co]);
}

__global__ void __launch_bounds__(256) conv_mid_k(const __hip_bfloat16* __restrict__ in,
                                                  const float* __restrict__ w,
                                                  const float* __restrict__ bias,
                                                  __hip_bfloat16* __restrict__ out, int relu) {
  __shared__ float tile[340];
  const int tx = threadIdx.x & 31, ty = threadIdx.x >> 5;
  const int x0 = blockIdx.x * 32, y0 = blockIdx.y * 8, b = blockIdx.z;
  float acc[64];
  #pragma unroll
  for (int co = 0; co < 64; ++co) acc[co] = bias[co];
  for (int ci = 0; ci < 64; ++ci) {
    __syncthreads();
    for (int e = threadIdx.x; e < 340; e += 256) {
      int iy = y0 - 1 + e / 34, ix = x0 - 1 + e % 34;
      float v = 0.f;
      if (iy >= 0 && iy < HH && ix >= 0 && ix < WW)
        v = __bfloat162float(in[(b*64+ci)*HW + iy*WW + ix]);
      tile[e] = v;
    }
    __syncthreads();
    float v0 = tile[ty*34+tx],     v1 = tile[ty*34+tx+1],     v2 = tile[ty*34+tx+2];
    float v3 = tile[(ty+1)*34+tx], v4 = tile[(ty+1)*34+tx+1], v5 = tile[(ty+1)*34+tx+2];
    float v6 = tile[(ty+2)*34+tx], v7 = tile[(ty+2)*34+tx+1], v8 = tile[(ty+2)*34+tx+2];
    const float* wci = w + ci*9;
    #pragma unroll
    for (int co = 0; co < 64; ++co) {
      const float* wp = wci + co*576;
      float a = acc[co];
      a = fmaf(v0, wp[0], a); a = fmaf(v1, wp[1], a); a = fmaf(v2, wp[2], a);
      a = fmaf(v3, wp[3], a); a = fmaf(v4, wp[4], a); a = fmaf(v5, wp[5], a);
      a = fmaf(v6, wp[6], a); a = fmaf(v7, wp[7], a); a = fmaf(v8, wp[8], a);
      acc[co] = a;
    }
  }
  const int oidx = (y0+ty)*WW + (x0+tx);
  #pragma unroll
  for (int co = 0; co < 64; ++co) {
    float vv = acc[co];
    if (relu) vv = fmaxf(vv, 0.f);
    out[(b*64+co)*HW + oidx] = __float2bfloat16(vv);
  }
}

// conv_out fused with: h = x + conv; v = under + lam*h; r=p=rhs=v; xc=0; rtr0 += |v|^2
__global__ void __launch_bounds__(256) conv_out_k(const __hip_bfloat16* __restrict__ in,
                                                  const float* __restrict__ w,
                                                  const float* __restrict__ bias,
                                                  const float* __restrict__ xcur,
                                                  const float* __restrict__ under,
                                                  const float* __restrict__ lam,
                                                  cf* __restrict__ r, cf* __restrict__ p,
                                                  cf* __restrict__ xc, float* __restrict__ rtr0) {
  __shared__ float tile[340];
  __shared__ float wsum[4];
  const int tx = threadIdx.x & 31, ty = threadIdx.x >> 5;
  const int x0 = blockIdx.x * 32, y0 = blockIdx.y * 8, b = blockIdx.z;
  float a0 = bias[0], a1 = bias[1];
  for (int ci = 0; ci < 64; ++ci) {
    __syncthreads();
    for (int e = threadIdx.x; e < 340; e += 256) {
      int iy = y0 - 1 + e / 34, ix = x0 - 1 + e % 34;
      float v = 0.f;
      if (iy >= 0 && iy < HH && ix >= 0 && ix < WW)
        v = __bfloat162float(in[(b*64+ci)*HW + iy*WW + ix]);
      tile[e] = v;
    }
    __syncthreads();
    float v0 = tile[ty*34+tx],     v1 = tile[ty*34+tx+1],     v2 = tile[ty*34+tx+2];
    float v3 = tile[(ty+1)*34+tx], v4 = tile[(ty+1)*34+tx+1], v5 = tile[(ty+1)*34+tx+2];
    float v6 = tile[(ty+2)*34+tx], v7 = tile[(ty+2)*34+tx+1], v8 = tile[(ty+2)*34+tx+2];
    const float* wp0 = w + ci*9;
    const float* wp1 = w + 576 + ci*9;
    a0 = fmaf(v0, wp0[0], a0); a0 = fmaf(v1, wp0[1], a0); a0 = fmaf(v2, wp0[2], a0);
    a0 = fmaf(v3, wp0[3], a0); a0 = fmaf(v4, wp0[4], a0); a0 = fmaf(v5, wp0[5], a0);
    a0 = fmaf(v6, wp0[6], a0); a0 = fmaf(v7, wp0[7], a0); a0 = fmaf(v8, wp0[8], a0);
    a1 = fmaf(v0, wp1[0], a1); a1 = fmaf(v1, wp1[1], a1); a1 = fmaf(v2, wp1[2], a1);
    a1 = fmaf(v3, wp1[3], a1); a1 = fmaf(v4, wp1[4], a1); a1 = fmaf(v5, wp1[5], a1);
    a1 = fmaf(v6, wp1[6], a1); a1 = fmaf(v7, wp1[7], a1); a1 = fmaf(v8, wp1[8], a1);
  }
  const float lamv = lam[0];
  const int idx2 = (y0+ty)*WW + (x0+tx);
  float xv0 = xcur[b*2*HW + idx2],      xv1 = xcur[b*2*HW + HW + idx2];
  float u0  = under[b*2*HW + idx2],     u1  = under[b*2*HW + HW + idx2];
  float r0 = u0 + lamv * (xv0 + a0);
  float r1 = u1 + lamv * (xv1 + a1);
  const int cidx = b*HW + idx2;
  cf vv; vv.x = r0; vv.y = r1;
  r[cidx] = vv; p[cidx] = vv;
  cf zz; zz.x = 0.f; zz.y = 0.f; xc[cidx] = zz;
  float partial = r0*r0 + r1*r1;
  for (int off = 32; off; off >>= 1) partial += __shfl_down(partial, off);
  const int l = threadIdx.x & 63, wvid = threadIdx.x >> 6;
  if (l == 0) wsum[wvid] = partial;
  __syncthreads();
  if (threadIdx.x == 0) atomicAdd(&rtr0[b], wsum[0]+wsum[1]+wsum[2]+wsum[3]);
}

// ---------------- CG / FFT kernels ----------------

// rows: t[b,c,y,:] = rowFFT( csm[b,c,y,:] * p[b,y,:] ); block0 zeroes pAp
__global__ void __launch_bounds__(256) pass_a_k(const cf* __restrict__ p, const cf* __restrict__ csm,
                                                cf* __restrict__ t, float* __restrict__ pAp) {
  __shared__ cf rowbuf[4][384];
  const int l = threadIdx.x & 63, wv = threadIdx.x >> 6;
  const int y = blockIdx.x * 4 + wv, b = blockIdx.y;
  if (blockIdx.x == 0 && b == 0 && threadIdx.x < BB) pAp[threadIdx.x] = 0.f;
  const cf* prow = p + b*HW + y*WW;
  cf pv[6];
  #pragma unroll
  for (int m = 0; m < 6; ++m) pv[m] = prow[l + 64*m];
  const int R3 = 3 * brev7(l);
  for (int c = 0; c < CC; ++c) {
    const cf* crow = csm + (b*CC + c)*HW + y*WW;
    cf v[6];
    #pragma unroll
    for (int m = 0; m < 6; ++m) v[m] = cmul(crow[l + 64*m], pv[m]);
    cf uA[3], uB[3];
    fft384_wave<-1>(l, v, uA, uB);
    __syncthreads();
    #pragma unroll
    for (int k1 = 0; k1 < 3; ++k1) { rowbuf[wv][k1 + R3] = uA[k1]; rowbuf[wv][k1 + R3 + 3] = uB[k1]; }
    __syncthreads();
    cf* trow = t + (b*CC + c)*HW + y*WW;
    #pragma unroll
    for (int m = 0; m < 6; ++m) trow[l + 64*m] = rowbuf[wv][l + 64*m];
  }
}

// cols: t = colIFFT( mask * colFFT(t) ) * (1/384)
__global__ void __launch_bounds__(256) pass_b_k(cf* __restrict__ t, const float* __restrict__ mask) {
  __shared__ cf tile[384*9];
  const int b = blockIdx.z, c = blockIdx.y, x0 = blockIdx.x * 8;
  cf* base = t + (b*CC + c)*HW;
  for (int e = threadIdx.x; e < 3072; e += 256) {
    int y = e >> 3, xx = e & 7;
    tile[y*9 + xx] = base[y*WW + x0 + xx];
  }
  __syncthreads();
  const int l = threadIdx.x & 63, wv = threadIdx.x >> 6;
  const int R3 = 3 * brev7(l);
  for (int rep = 0; rep < 2; ++rep) {
    const int xx = wv*2 + rep, x = x0 + xx;
    cf v[6];
    #pragma unroll
    for (int m = 0; m < 6; ++m) v[m] = tile[(l + 64*m)*9 + xx];
    cf uA[3], uB[3];
    fft384_wave<-1>(l, v, uA, uB);
    const float* mrow = mask + b*HW + x;
    #pragma unroll
    for (int k1 = 0; k1 < 3; ++k1) {
      float mA = mrow[(k1 + R3)*WW], mB = mrow[(k1 + R3 + 3)*WW];
      uA[k1].x *= mA; uA[k1].y *= mA; uB[k1].x *= mB; uB[k1].y *= mB;
    }
    __syncthreads();
    #pragma unroll
    for (int k1 = 0; k1 < 3; ++k1) { tile[(k1 + R3)*9 + xx] = uA[k1]; tile[(k1 + R3 + 3)*9 + xx] = uB[k1]; }
    __syncthreads();
    #pragma unroll
    for (int m = 0; m < 6; ++m) v[m] = tile[(l + 64*m)*9 + xx];
    fft384_wave<1>(l, v, uA, uB);
    const float s = 1.0f / 384.0f;
    #pragma unroll
    for (int k1 = 0; k1 < 3; ++k1) {
      uA[k1].x *= s; uA[k1].y *= s; uB[k1].x *= s; uB[k1].y *= s;
      tile[(k1 + R3)*9 + xx] = uA[k1]; tile[(k1 + R3 + 3)*9 + xx] = uB[k1];
    }
    __syncthreads();
  }
  for (int e = threadIdx.x; e < 3072; e += 256) {
    int y = e >> 3, xx = e & 7;
    base[y*WW + x0 + xx] = tile[y*9 + xx];
  }
}

// rows: Ap[b,y,:] = (1/384) * sum_c conj(csm)*rowIFFT(t) + lam*p;  pAp[b] += Re(conj(p)*Ap)
__global__ void __launch_bounds__(256) pass_c_k(const cf* __restrict__ t, const cf* __restrict__ csm,
                                                const cf* __restrict__ p, cf* __restrict__ Ap,
                                                const float* __restrict__ lam, float* __restrict__ pAp) {
  __shared__ cf rowbuf[4][384];
  __shared__ float wsum[4];
  const int l = threadIdx.x & 63, wv = threadIdx.x >> 6;
  const int y = blockIdx.x * 4 + wv, b = blockIdx.y;
  const int R3 = 3 * brev7(l);
  cf acc[6] = {};
  for (int c = 0; c < CC; ++c) {
    const cf* trow = t + (b*CC + c)*HW + y*WW;
    cf v[6];
    #pragma unroll
    for (int m = 0; m < 6; ++m) v[m] = trow[l + 64*m];
    cf uA[3], uB[3];
    fft384_wave<1>(l, v, uA, uB);
    __syncthreads();
    #pragma unroll
    for (int k1 = 0; k1 < 3; ++k1) { rowbuf[wv][k1 + R3] = uA[k1]; rowbuf[wv][k1 + R3 + 3] = uB[k1]; }
    __syncthreads();
    const cf* crow = csm + (b*CC + c)*HW + y*WW;
    #pragma unroll
    for (int m = 0; m < 6; ++m) {
      cf cs = crow[l + 64*m];
      cf wz = rowbuf[wv][l + 64*m];
      acc[m].x += cs.x*wz.x + cs.y*wz.y;   // conj(cs)*wz
      acc[m].y += cs.x*wz.y - cs.y*wz.x;
    }
  }
  const float lamv = lam[0];
  const float sc384 = 1.0f / 384.0f;
  const cf* prow = p + b*HW + y*WW;
  cf* aprow = Ap + b*HW + y*WW;
  float partial = 0.f;
  #pragma unroll
  for (int m = 0; m < 6; ++m) {
    cf pv = prow[l + 64*m];
    cf ap; ap.x = acc[m].x*sc384 + lamv*pv.x; ap.y = acc[m].y*sc384 + lamv*pv.y;
    aprow[l + 64*m] = ap;
    partial += pv.x*ap.x + pv.y*ap.y;
  }
  for (int off = 32; off; off >>= 1) partial += __shfl_down(partial, off);
  if (l == 0) wsum[wv] = partial;
  __syncthreads();
  if (threadIdx.x == 0) atomicAdd(&pAp[b], wsum[0]+wsum[1]+wsum[2]+wsum[3]);
}

__global__ void __launch_bounds__(256) upd1_k(cf* __restrict__ x, cf* __restrict__ r,
                                              const cf* __restrict__ p, const cf* __restrict__ Ap,
                                              const float* __restrict__ rtr_cur,
                                              const float* __restrict__ pAp,
                                              float* __restrict__ rtr_next) {
  __shared__ float wsum[4];
  const int idx = blockIdx.x * 256 + threadIdx.x;
  const int b = idx / HW;
  const float alpha = rtr_cur[b] / pAp[b];
  cf pv = p[idx], apv = Ap[idx];
  cf xv = x[idx]; xv.x += alpha*pv.x; xv.y += alpha*pv.y; x[idx] = xv;
  cf rv = r[idx]; rv.x -= alpha*apv.x; rv.y -= alpha*apv.y; r[idx] = rv;
  float partial = rv.x*rv.x + rv.y*rv.y;
  for (int off = 32; off; off >>= 1) partial += __shfl_down(partial, off);
  const int l = threadIdx.x & 63, wv = threadIdx.x >> 6;
  if (l == 0) wsum[wv] = partial;
  __syncthreads();
  if (threadIdx.x == 0) atomicAdd(&rtr_next[b], wsum[0]+wsum[1]+wsum[2]+wsum[3]);
}

__global__ void __launch_bounds__(256) upd2_k(cf* __restrict__ p, const cf* __restrict__ r,
                                              const float* __restrict__ rtr_new,
                                              const float* __restrict__ rtr_old) {
  const int idx = blockIdx.x * 256 + threadIdx.x;
  const int b = idx / HW;
  const float beta = rtr_new[b] / rtr_old[b];
  cf pv = p[idx], rv = r[idx];
  cf o; o.x = rv.x + beta*pv.x; o.y = rv.y + beta*pv.y;
  p[idx] = o;
}

__global__ void __launch_bounds__(256) store_x_k(const cf* __restrict__ xc, float* __restrict__ out) {
  const int idx = blockIdx.x * 256 + threadIdx.x;
  const int b = idx / HW;
  const int rem = idx - b*HW;
  cf v = xc[idx];
  out[b*2*HW + rem] = v.x;
  out[b*2*HW + HW + rem] = v.y;
}

__global__ void zero_sc_k(float* sc) { if (threadIdx.x < 64) sc[threadIdx.x] = 0.f; }

extern "C" void kernel_launch(void* const* d_in, const int* in_sizes, int n_in,
                              void* d_out, int out_size, void* d_ws, size_t ws_size,
                              hipStream_t stream) {
  (void)in_sizes; (void)n_in; (void)out_size; (void)ws_size;
  const float* under  = (const float*)d_in[0];
  const cf*    csm    = (const cf*)d_in[1];
  const float* mask   = (const float*)d_in[2];
  const float* lam    = (const float*)d_in[3];
  const float* w_in   = (const float*)d_in[4];
  const float* b_in   = (const float*)d_in[5];
  const float* ws_mid = (const float*)d_in[6];
  const float* bs_mid = (const float*)d_in[7];
  const float* w_out  = (const float*)d_in[8];
  const float* b_out  = (const float*)d_in[9];
  float* xcur = (float*)d_out;

  char* bws = (char*)d_ws;
  size_t off = 0;
  auto carve = [&](size_t bytes) { char* pp = bws + off; off += (bytes + 255) & ~(size_t)255; return (void*)pp; };
  __hip_bfloat16* actA = (__hip_bfloat16*)carve((size_t)BB*64*HW*2);
  __hip_bfloat16* actB = (__hip_bfloat16*)carve((size_t)BB*64*HW*2);
  cf* t    = (cf*)carve((size_t)BB*CC*HW*8);
  cf* r    = (cf*)carve((size_t)BB*HW*8);
  cf* pbuf = (cf*)carve((size_t)BB*HW*8);
  cf* xc   = (cf*)carve((size_t)BB*HW*8);
  cf* Ap   = (cf*)carve((size_t)BB*HW*8);
  float* sc = (float*)carve(256*4);

  hipMemcpyAsync(xcur, under, (size_t)BB*2*HW*sizeof(float), hipMemcpyDeviceToDevice, stream);

  dim3 cgrid(WW/32, HH/8, BB);
  dim3 rowgrid(HH/4, BB);
  dim3 colgrid(WW/8, CC, BB);
  const int egrid = BB*HW/256;

  __hip_bfloat16* bufs[2] = { actA, actB };

  for (int layer = 0; layer < NLAYERS; ++layer) {
    zero_sc_k<<<1, 64, 0, stream>>>(sc);
    conv_in_k<<<cgrid, 256, 0, stream>>>(xcur, w_in, b_in, bufs[0]);
    for (int i = 0; i < 7; ++i) {
      conv_mid_k<<<cgrid, 256, 0, stream>>>(bufs[i & 1], ws_mid + (size_t)i*64*64*9,
                                            bs_mid + i*64, bufs[(i + 1) & 1], (i % 2 == 0) ? 1 : 0);
    }
    conv_out_k<<<cgrid, 256, 0, stream>>>(bufs[1], w_out, b_out, xcur, under, lam,
                                          r, pbuf, xc, sc + 4);
    for (int it = 0; it < CGITERS; ++it) {
      pass_a_k<<<rowgrid, 256, 0, stream>>>(pbuf, csm, t, sc);
      pass_b_k<<<colgrid, 256, 0, stream>>>(t, mask);
      pass_c_k<<<rowgrid, 256, 0, stream>>>(t, csm, pbuf, Ap, lam, sc);
      upd1_k<<<egrid, 256, 0, stream>>>(xc, r, pbuf, Ap, sc + 4 + it*4, sc, sc + 4 + (it+1)*4);
      if (it < CGITERS - 1)
        upd2_k<<<egrid, 256, 0, stream>>>(pbuf, r, sc + 4 + (it+1)*4, sc + 4 + it*4);
    }
    store_x_k<<<egrid, 256, 0, stream>>>(xc, xcur);
  }
}

// Round 2
// 15504.573 us; speedup vs baseline: 2.8069x; 2.8069x over previous
//
#include <hip/hip_runtime.h>
#include <hip/hip_bf16.h>
#include <math.h>

#define HH 384
#define WW 384
#define HW (HH*WW)
#define BB 4
#define CC 8
#define NLAYERS 5
#define CGITERS 10
#define PI_F 3.14159265358979323846f

typedef __attribute__((ext_vector_type(8))) short short8;
typedef __attribute__((ext_vector_type(4))) float floatx4;

struct cf { float x, y; };
__device__ __forceinline__ cf cadd(cf a, cf b){ cf r; r.x=a.x+b.x; r.y=a.y+b.y; return r; }
__device__ __forceinline__ cf csub(cf a, cf b){ cf r; r.x=a.x-b.x; r.y=a.y-b.y; return r; }
__device__ __forceinline__ cf cmul(cf a, cf b){ cf r; r.x=a.x*b.x - a.y*b.y; r.y=a.x*b.y + a.y*b.x; return r; }
__device__ __forceinline__ cf shflxor(cf v, int m){ cf r; r.x = __shfl_xor(v.x, m); r.y = __shfl_xor(v.y, m); return r; }
__device__ __forceinline__ int brev7(int l){ return (int)(__brev((unsigned)l) >> 25); }

__device__ __forceinline__ void radix3(cf a0, cf a1, cf a2, float s3, cf y[3]) {
  float tx = a1.x + a2.x, ty_ = a1.y + a2.y;
  float ux = a1.x - a2.x, uy = a1.y - a2.y;
  y[0].x = a0.x + tx;              y[0].y = a0.y + ty_;
  y[1].x = a0.x - 0.5f*tx - s3*uy; y[1].y = a0.y - 0.5f*ty_ + s3*ux;
  y[2].x = a0.x - 0.5f*tx + s3*uy; y[2].y = a0.y - 0.5f*ty_ - s3*ux;
}

// 384-point DFT across one 64-lane wave. SIGN=-1 fwd, +1 inverse (no 1/N scale).
template<int SIGN>
__device__ __forceinline__ void fft384_wave(int l, const cf v[6], cf uA[3], cf uB[3]) {
  const float s3 = SIGN * 0.8660254037844386f;
  radix3(v[0], v[2], v[4], s3, uA);
  radix3(v[1], v[3], v[5], s3, uB);
  const float base = SIGN * (2.0f * PI_F / 384.0f);
  float sA, cA; __sincosf(base * (float)l, &sA, &cA);
  cf wA1; wA1.x = cA; wA1.y = sA; cf wA2 = cmul(wA1, wA1);
  float sB, cB; __sincosf(base * (float)(l + 64), &sB, &cB);
  cf wB1; wB1.x = cB; wB1.y = sB; cf wB2 = cmul(wB1, wB1);
  uA[1] = cmul(uA[1], wA1); uA[2] = cmul(uA[2], wA2);
  uB[1] = cmul(uB[1], wB1); uB[2] = cmul(uB[2], wB2);
  {
    float s, c; __sincosf(SIGN * (PI_F/64.0f) * (float)l, &s, &c);
    cf w; w.x = c; w.y = s;
    #pragma unroll
    for (int k1 = 0; k1 < 3; ++k1) {
      cf a = uA[k1], b = uB[k1];
      uA[k1] = cadd(a, b);
      uB[k1] = cmul(csub(a, b), w);
    }
  }
  #pragma unroll
  for (int h = 32; h >= 1; h >>= 1) {
    const int j = l & (h - 1);
    float s, c; __sincosf(SIGN * PI_F * (float)j / (float)h, &s, &c);
    cf w; w.x = c; w.y = s;
    const bool up = (l & h) != 0;
    #pragma unroll
    for (int k1 = 0; k1 < 3; ++k1) {
      cf pa = shflxor(uA[k1], h);
      cf pb = shflxor(uB[k1], h);
      cf na = up ? cmul(csub(pa, uA[k1]), w) : cadd(uA[k1], pa);
      cf nb = up ? cmul(csub(pb, uB[k1]), w) : cadd(uB[k1], pb);
      uA[k1] = na; uB[k1] = nb;
    }
  }
}

// ---------------- conv kernels ----------------
// Activations live in NHWC bf16: act[b][y][x][c], c=64 contiguous.

// repack ws_mid [7][64][64][3][3] fp32 -> wrep [7][9][64][64] bf16 (ci contiguous)
__global__ void repack_mid_k(const float* __restrict__ ws_mid, __hip_bfloat16* __restrict__ wrep) {
  const int idx = blockIdx.x * 256 + threadIdx.x;
  if (idx >= 7*9*64*64) return;
  const int ci = idx & 63, co = (idx >> 6) & 63, tap = (idx >> 12) % 9, i = idx / (9*4096);
  wrep[idx] = __float2bfloat16(ws_mid[(((size_t)i*64 + co)*64 + ci)*9 + tap]);
}

__global__ void __launch_bounds__(256) conv_in_k(const float* __restrict__ xin,
                                                 const float* __restrict__ w,
                                                 const float* __restrict__ bias,
                                                 __hip_bfloat16* __restrict__ out) {
  __shared__ float tile[2][340];
  const int tx = threadIdx.x & 31, ty = threadIdx.x >> 5;
  const int x0 = blockIdx.x * 32, y0 = blockIdx.y * 8, b = blockIdx.z;
  for (int e = threadIdx.x; e < 680; e += 256) {
    int ci = e / 340, rr = e % 340;
    int iy = y0 - 1 + rr / 34, ix = x0 - 1 + rr % 34;
    float v = 0.f;
    if (iy >= 0 && iy < HH && ix >= 0 && ix < WW)
      v = xin[(b*2 + ci)*HW + iy*WW + ix];
    tile[ci][rr] = v;
  }
  __syncthreads();
  float acc[64];
  #pragma unroll
  for (int co = 0; co < 64; ++co) acc[co] = bias[co];
  #pragma unroll
  for (int ci = 0; ci < 2; ++ci) {
    float v0 = tile[ci][ty*34+tx],     v1 = tile[ci][ty*34+tx+1],     v2 = tile[ci][ty*34+tx+2];
    float v3 = tile[ci][(ty+1)*34+tx], v4 = tile[ci][(ty+1)*34+tx+1], v5 = tile[ci][(ty+1)*34+tx+2];
    float v6 = tile[ci][(ty+2)*34+tx], v7 = tile[ci][(ty+2)*34+tx+1], v8 = tile[ci][(ty+2)*34+tx+2];
    #pragma unroll
    for (int co = 0; co < 64; ++co) {
      const float* wp = w + co*18 + ci*9;
      float a = acc[co];
      a = fmaf(v0, wp[0], a); a = fmaf(v1, wp[1], a); a = fmaf(v2, wp[2], a);
      a = fmaf(v3, wp[3], a); a = fmaf(v4, wp[4], a); a = fmaf(v5, wp[5], a);
      a = fmaf(v6, wp[6], a); a = fmaf(v7, wp[7], a); a = fmaf(v8, wp[8], a);
      acc[co] = a;
    }
  }
  const size_t obase = ((size_t)(b*HH + y0 + ty)*WW + (x0 + tx))*64;
  #pragma unroll
  for (int s = 0; s < 8; ++s) {
    uint4 u;
    __hip_bfloat16* hp = (__hip_bfloat16*)&u;
    #pragma unroll
    for (int j = 0; j < 8; ++j) hp[j] = __float2bfloat16(acc[s*8 + j]);
    *(uint4*)(out + obase + s*8) = u;
  }
}

// MFMA implicit-GEMM mid conv: M=256 pixels (32x8 tile), N=64 couts, K=576 (9 taps x 64ci)
__global__ void __launch_bounds__(256) conv_mid_mfma_k(
    const __hip_bfloat16* __restrict__ in,    // NHWC
    const __hip_bfloat16* __restrict__ wrep,  // [9][64][64] bf16 for this conv
    const float* __restrict__ bias,
    __hip_bfloat16* __restrict__ out, int relu) {
  __shared__ __hip_bfloat16 atile[10*34*72];  // halo tile, ch padded 64->72 (48960 B)
  __shared__ __hip_bfloat16 wtile[64*72];     // per-tap weights [co][ci pad 72] (9216 B)
  const int tid = threadIdx.x;
  const int l = tid & 63, wv = tid >> 6;
  const int x0 = blockIdx.x * 32, y0 = blockIdx.y * 8, b = blockIdx.z;

  // stage activation halo (10x34 pixels x 64ch), 16B per element-load
  for (int e = tid; e < 340*8; e += 256) {
    int p = e >> 3, s = e & 7;
    int iy = y0 - 1 + p / 34, ix = x0 - 1 + p % 34;
    uint4 v = make_uint4(0u, 0u, 0u, 0u);
    if (iy >= 0 && iy < HH && ix >= 0 && ix < WW)
      v = *(const uint4*)(in + ((size_t)(b*HH + iy)*WW + ix)*64 + s*8);
    *(uint4*)(&atile[p*72 + s*8]) = v;
  }

  floatx4 acc[4][4];
  #pragma unroll
  for (int mt = 0; mt < 4; ++mt)
    #pragma unroll
    for (int nt = 0; nt < 4; ++nt)
      acc[mt][nt] = (floatx4){0.f, 0.f, 0.f, 0.f};

  const int kseg = l >> 4;   // 0..3 (k = kseg*8 + j within a 32-chunk)
  const int lr = l & 15;

  for (int tap = 0; tap < 9; ++tap) {
    __syncthreads();
    for (int e = tid; e < 512; e += 256) {
      int co = e >> 3, s = e & 7;
      *(uint4*)(&wtile[co*72 + s*8]) = *(const uint4*)(wrep + tap*4096 + co*64 + s*8);
    }
    __syncthreads();
    const int dy = tap / 3, dx = tap - dy*3;
    short8 af[4][2], bf[4][2];
    #pragma unroll
    for (int mt = 0; mt < 4; ++mt) {
      const int ry = 2*wv + (mt >> 1) + dy;
      const int px = (mt & 1)*16 + lr + dx;
      const __hip_bfloat16* ap = &atile[(ry*34 + px)*72 + kseg*8];
      af[mt][0] = *(const short8*)(ap);
      af[mt][1] = *(const short8*)(ap + 32);
    }
    #pragma unroll
    for (int nt = 0; nt < 4; ++nt) {
      const __hip_bfloat16* bp = &wtile[(nt*16 + lr)*72 + kseg*8];
      bf[nt][0] = *(const short8*)(bp);
      bf[nt][1] = *(const short8*)(bp + 32);
    }
    #pragma unroll
    for (int mt = 0; mt < 4; ++mt)
      #pragma unroll
      for (int nt = 0; nt < 4; ++nt) {
        acc[mt][nt] = __builtin_amdgcn_mfma_f32_16x16x32_bf16(af[mt][0], bf[nt][0], acc[mt][nt], 0, 0, 0);
        acc[mt][nt] = __builtin_amdgcn_mfma_f32_16x16x32_bf16(af[mt][1], bf[nt][1], acc[mt][nt], 0, 0, 0);
      }
  }

  // epilogue: D[i][j]: i = 4*(l>>4)+r (pixel-within-16), j = l&15 (cout-within-16)
  #pragma unroll
  for (int nt = 0; nt < 4; ++nt) {
    const float bv = bias[nt*16 + lr];
    #pragma unroll
    for (int mt = 0; mt < 4; ++mt) {
      const int ry = 2*wv + (mt >> 1);
      const int xb = (mt & 1)*16 + kseg*4;
      #pragma unroll
      for (int rr = 0; rr < 4; ++rr) {
        float v = acc[mt][nt][rr] + bv;
        if (relu) v = fmaxf(v, 0.f);
        out[((size_t)(b*HH + y0 + ry)*WW + (x0 + xb + rr))*64 + nt*16 + lr] = __float2bfloat16(v);
      }
    }
  }
}

// conv_out (co=2) fused with CG init; reads NHWC bf16
__global__ void __launch_bounds__(256) conv_out_k(const __hip_bfloat16* __restrict__ in,
                                                  const float* __restrict__ w,
                                                  const float* __restrict__ bias,
                                                  const float* __restrict__ xcur,
                                                  const float* __restrict__ under,
                                                  const float* __restrict__ lam,
                                                  cf* __restrict__ r, cf* __restrict__ p,
                                                  cf* __restrict__ xc, float* __restrict__ rtr0) {
  __shared__ float wl[2*64*9];   // w_out[co][ci][tap] flat
  __shared__ float wsum[4];
  const int tx = threadIdx.x & 31, ty = threadIdx.x >> 5;
  const int x0 = blockIdx.x * 32, y0 = blockIdx.y * 8, b = blockIdx.z;
  for (int e = threadIdx.x; e < 2*64*9; e += 256) wl[e] = w[e];
  __syncthreads();
  const int y = y0 + ty, x = x0 + tx;
  float a0 = bias[0], a1 = bias[1];
  for (int tap = 0; tap < 9; ++tap) {
    const int iy = y + tap/3 - 1, ix = x + tap%3 - 1;
    if (iy < 0 || iy >= HH || ix < 0 || ix >= WW) continue;
    const __hip_bfloat16* pp = in + ((size_t)(b*HH + iy)*WW + ix)*64;
    #pragma unroll
    for (int s = 0; s < 8; ++s) {
      uint4 v = *(const uint4*)(pp + s*8);
      const __hip_bfloat16* hv = (const __hip_bfloat16*)&v;
      #pragma unroll
      for (int j = 0; j < 8; ++j) {
        const float f = __bfloat162float(hv[j]);
        a0 = fmaf(f, wl[(s*8 + j)*9 + tap], a0);
        a1 = fmaf(f, wl[(64 + s*8 + j)*9 + tap], a1);
      }
    }
  }
  const float lamv = lam[0];
  const int idx2 = y*WW + x;
  float xv0 = xcur[b*2*HW + idx2],  xv1 = xcur[b*2*HW + HW + idx2];
  float u0  = under[b*2*HW + idx2], u1  = under[b*2*HW + HW + idx2];
  float r0 = u0 + lamv * (xv0 + a0);
  float r1 = u1 + lamv * (xv1 + a1);
  const int cidx = b*HW + idx2;
  cf vv; vv.x = r0; vv.y = r1;
  r[cidx] = vv; p[cidx] = vv;
  cf zz; zz.x = 0.f; zz.y = 0.f; xc[cidx] = zz;
  float partial = r0*r0 + r1*r1;
  for (int off = 32; off; off >>= 1) partial += __shfl_down(partial, off);
  const int l = threadIdx.x & 63, wvid = threadIdx.x >> 6;
  if (l == 0) wsum[wvid] = partial;
  __syncthreads();
  if (threadIdx.x == 0) atomicAdd(&rtr0[b], wsum[0]+wsum[1]+wsum[2]+wsum[3]);
}

// ---------------- CG / FFT kernels ----------------

__global__ void __launch_bounds__(256) pass_a_k(const cf* __restrict__ p, const cf* __restrict__ csm,
                                                cf* __restrict__ t, float* __restrict__ pAp) {
  __shared__ cf rowbuf[4][384];
  const int l = threadIdx.x & 63, wv = threadIdx.x >> 6;
  const int y = blockIdx.x * 4 + wv, b = blockIdx.y;
  if (blockIdx.x == 0 && b == 0 && threadIdx.x < BB) pAp[threadIdx.x] = 0.f;
  const cf* prow = p + b*HW + y*WW;
  cf pv[6];
  #pragma unroll
  for (int m = 0; m < 6; ++m) pv[m] = prow[l + 64*m];
  const int R3 = 3 * brev7(l);
  for (int c = 0; c < CC; ++c) {
    const cf* crow = csm + (b*CC + c)*HW + y*WW;
    cf v[6];
    #pragma unroll
    for (int m = 0; m < 6; ++m) v[m] = cmul(crow[l + 64*m], pv[m]);
    cf uA[3], uB[3];
    fft384_wave<-1>(l, v, uA, uB);
    __syncthreads();
    #pragma unroll
    for (int k1 = 0; k1 < 3; ++k1) { rowbuf[wv][k1 + R3] = uA[k1]; rowbuf[wv][k1 + R3 + 3] = uB[k1]; }
    __syncthreads();
    cf* trow = t + (b*CC + c)*HW + y*WW;
    #pragma unroll
    for (int m = 0; m < 6; ++m) trow[l + 64*m] = rowbuf[wv][l + 64*m];
  }
}

__global__ void __launch_bounds__(256) pass_b_k(cf* __restrict__ t, const float* __restrict__ mask) {
  __shared__ cf tile[384*9];
  const int b = blockIdx.z, c = blockIdx.y, x0 = blockIdx.x * 8;
  cf* base = t + (b*CC + c)*HW;
  for (int e = threadIdx.x; e < 3072; e += 256) {
    int y = e >> 3, xx = e & 7;
    tile[y*9 + xx] = base[y*WW + x0 + xx];
  }
  __syncthreads();
  const int l = threadIdx.x & 63, wv = threadIdx.x >> 6;
  const int R3 = 3 * brev7(l);
  for (int rep = 0; rep < 2; ++rep) {
    const int xx = wv*2 + rep, x = x0 + xx;
    cf v[6];
    #pragma unroll
    for (int m = 0; m < 6; ++m) v[m] = tile[(l + 64*m)*9 + xx];
    cf uA[3], uB[3];
    fft384_wave<-1>(l, v, uA, uB);
    const float* mrow = mask + b*HW + x;
    #pragma unroll
    for (int k1 = 0; k1 < 3; ++k1) {
      float mA = mrow[(k1 + R3)*WW], mB = mrow[(k1 + R3 + 3)*WW];
      uA[k1].x *= mA; uA[k1].y *= mA; uB[k1].x *= mB; uB[k1].y *= mB;
    }
    __syncthreads();
    #pragma unroll
    for (int k1 = 0; k1 < 3; ++k1) { tile[(k1 + R3)*9 + xx] = uA[k1]; tile[(k1 + R3 + 3)*9 + xx] = uB[k1]; }
    __syncthreads();
    #pragma unroll
    for (int m = 0; m < 6; ++m) v[m] = tile[(l + 64*m)*9 + xx];
    fft384_wave<1>(l, v, uA, uB);
    const float s = 1.0f / 384.0f;
    #pragma unroll
    for (int k1 = 0; k1 < 3; ++k1) {
      uA[k1].x *= s; uA[k1].y *= s; uB[k1].x *= s; uB[k1].y *= s;
      tile[(k1 + R3)*9 + xx] = uA[k1]; tile[(k1 + R3 + 3)*9 + xx] = uB[k1];
    }
    __syncthreads();
  }
  for (int e = threadIdx.x; e < 3072; e += 256) {
    int y = e >> 3, xx = e & 7;
    base[y*WW + x0 + xx] = tile[y*9 + xx];
  }
}

__global__ void __launch_bounds__(256) pass_c_k(const cf* __restrict__ t, const cf* __restrict__ csm,
                                                const cf* __restrict__ p, cf* __restrict__ Ap,
                                                const float* __restrict__ lam, float* __restrict__ pAp) {
  __shared__ cf rowbuf[4][384];
  __shared__ float wsum[4];
  const int l = threadIdx.x & 63, wv = threadIdx.x >> 6;
  const int y = blockIdx.x * 4 + wv, b = blockIdx.y;
  const int R3 = 3 * brev7(l);
  cf acc[6] = {};
  for (int c = 0; c < CC; ++c) {
    const cf* trow = t + (b*CC + c)*HW + y*WW;
    cf v[6];
    #pragma unroll
    for (int m = 0; m < 6; ++m) v[m] = trow[l + 64*m];
    cf uA[3], uB[3];
    fft384_wave<1>(l, v, uA, uB);
    __syncthreads();
    #pragma unroll
    for (int k1 = 0; k1 < 3; ++k1) { rowbuf[wv][k1 + R3] = uA[k1]; rowbuf[wv][k1 + R3 + 3] = uB[k1]; }
    __syncthreads();
    const cf* crow = csm + (b*CC + c)*HW + y*WW;
    #pragma unroll
    for (int m = 0; m < 6; ++m) {
      cf cs = crow[l + 64*m];
      cf wz = rowbuf[wv][l + 64*m];
      acc[m].x += cs.x*wz.x + cs.y*wz.y;
      acc[m].y += cs.x*wz.y - cs.y*wz.x;
    }
  }
  const float lamv = lam[0];
  const float sc384 = 1.0f / 384.0f;
  const cf* prow = p + b*HW + y*WW;
  cf* aprow = Ap + b*HW + y*WW;
  float partial = 0.f;
  #pragma unroll
  for (int m = 0; m < 6; ++m) {
    cf pv = prow[l + 64*m];
    cf ap; ap.x = acc[m].x*sc384 + lamv*pv.x; ap.y = acc[m].y*sc384 + lamv*pv.y;
    aprow[l + 64*m] = ap;
    partial += pv.x*ap.x + pv.y*ap.y;
  }
  for (int off = 32; off; off >>= 1) partial += __shfl_down(partial, off);
  if (l == 0) wsum[wv] = partial;
  __syncthreads();
  if (threadIdx.x == 0) atomicAdd(&pAp[b], wsum[0]+wsum[1]+wsum[2]+wsum[3]);
}

__global__ void __launch_bounds__(256) upd1_k(cf* __restrict__ x, cf* __restrict__ r,
                                              const cf* __restrict__ p, const cf* __restrict__ Ap,
                                              const float* __restrict__ rtr_cur,
                                              const float* __restrict__ pAp,
                                              float* __restrict__ rtr_next) {
  __shared__ float wsum[4];
  const int idx = blockIdx.x * 256 + threadIdx.x;
  const int b = idx / HW;
  const float alpha = rtr_cur[b] / pAp[b];
  cf pv = p[idx], apv = Ap[idx];
  cf xv = x[idx]; xv.x += alpha*pv.x; xv.y += alpha*pv.y; x[idx] = xv;
  cf rv = r[idx]; rv.x -= alpha*apv.x; rv.y -= alpha*apv.y; r[idx] = rv;
  float partial = rv.x*rv.x + rv.y*rv.y;
  for (int off = 32; off; off >>= 1) partial += __shfl_down(partial, off);
  const int l = threadIdx.x & 63, wv = threadIdx.x >> 6;
  if (l == 0) wsum[wv] = partial;
  __syncthreads();
  if (threadIdx.x == 0) atomicAdd(&rtr_next[b], wsum[0]+wsum[1]+wsum[2]+wsum[3]);
}

__global__ void __launch_bounds__(256) upd2_k(cf* __restrict__ p, const cf* __restrict__ r,
                                              const float* __restrict__ rtr_new,
                                              const float* __restrict__ rtr_old) {
  const int idx = blockIdx.x * 256 + threadIdx.x;
  const int b = idx / HW;
  const float beta = rtr_new[b] / rtr_old[b];
  cf pv = p[idx], rv = r[idx];
  cf o; o.x = rv.x + beta*pv.x; o.y = rv.y + beta*pv.y;
  p[idx] = o;
}

__global__ void __launch_bounds__(256) store_x_k(const cf* __restrict__ xc, float* __restrict__ out) {
  const int idx = blockIdx.x * 256 + threadIdx.x;
  const int b = idx / HW;
  const int rem = idx - b*HW;
  cf v = xc[idx];
  out[b*2*HW + rem] = v.x;
  out[b*2*HW + HW + rem] = v.y;
}

__global__ void zero_sc_k(float* sc) { if (threadIdx.x < 64) sc[threadIdx.x] = 0.f; }

extern "C" void kernel_launch(void* const* d_in, const int* in_sizes, int n_in,
                              void* d_out, int out_size, void* d_ws, size_t ws_size,
                              hipStream_t stream) {
  (void)in_sizes; (void)n_in; (void)out_size; (void)ws_size;
  const float* under  = (const float*)d_in[0];
  const cf*    csm    = (const cf*)d_in[1];
  const float* mask   = (const float*)d_in[2];
  const float* lam    = (const float*)d_in[3];
  const float* w_in   = (const float*)d_in[4];
  const float* b_in   = (const float*)d_in[5];
  const float* ws_mid = (const float*)d_in[6];
  const float* bs_mid = (const float*)d_in[7];
  const float* w_out  = (const float*)d_in[8];
  const float* b_out  = (const float*)d_in[9];
  float* xcur = (float*)d_out;

  char* bws = (char*)d_ws;
  size_t off = 0;
  auto carve = [&](size_t bytes) { char* pp = bws + off; off += (bytes + 255) & ~(size_t)255; return (void*)pp; };
  __hip_bfloat16* actA = (__hip_bfloat16*)carve((size_t)BB*64*HW*2);
  __hip_bfloat16* actB = (__hip_bfloat16*)carve((size_t)BB*64*HW*2);
  cf* t    = (cf*)carve((size_t)BB*CC*HW*8);
  cf* r    = (cf*)carve((size_t)BB*HW*8);
  cf* pbuf = (cf*)carve((size_t)BB*HW*8);
  cf* xc   = (cf*)carve((size_t)BB*HW*8);
  cf* Ap   = (cf*)carve((size_t)BB*HW*8);
  float* sc = (float*)carve(256*4);
  __hip_bfloat16* wrep = (__hip_bfloat16*)carve((size_t)7*9*64*64*2);

  hipMemcpyAsync(xcur, under, (size_t)BB*2*HW*sizeof(float), hipMemcpyDeviceToDevice, stream);

  repack_mid_k<<<(7*9*64*64 + 255)/256, 256, 0, stream>>>(ws_mid, wrep);

  dim3 cgrid(WW/32, HH/8, BB);
  dim3 rowgrid(HH/4, BB);
  dim3 colgrid(WW/8, CC, BB);
  const int egrid = BB*HW/256;

  __hip_bfloat16* bufs[2] = { actA, actB };

  for (int layer = 0; layer < NLAYERS; ++layer) {
    zero_sc_k<<<1, 64, 0, stream>>>(sc);
    conv_in_k<<<cgrid, 256, 0, stream>>>(xcur, w_in, b_in, bufs[0]);
    for (int i = 0; i < 7; ++i) {
      conv_mid_mfma_k<<<cgrid, 256, 0, stream>>>(bufs[i & 1], wrep + (size_t)i*9*4096,
                                                 bs_mid + i*64, bufs[(i + 1) & 1], (i % 2 == 0) ? 1 : 0);
    }
    conv_out_k<<<cgrid, 256, 0, stream>>>(bufs[1], w_out, b_out, xcur, under, lam,
                                          r, pbuf, xc, sc + 4);
    for (int it = 0; it < CGITERS; ++it) {
      pass_a_k<<<rowgrid, 256, 0, stream>>>(pbuf, csm, t, sc);
      pass_b_k<<<colgrid, 256, 0, stream>>>(t, mask);
      pass_c_k<<<rowgrid, 256, 0, stream>>>(t, csm, pbuf, Ap, lam, sc);
      upd1_k<<<egrid, 256, 0, stream>>>(xc, r, pbuf, Ap, sc + 4 + it*4, sc, sc + 4 + (it+1)*4);
      if (it < CGITERS - 1)
        upd2_k<<<egrid, 256, 0, stream>>>(pbuf, r, sc + 4 + (it+1)*4, sc + 4 + it*4);
    }
    store_x_k<<<egrid, 256, 0, stream>>>(xc, xcur);
  }
}

// Round 3
// 15361.111 us; speedup vs baseline: 2.8331x; 1.0093x over previous
//
#include <hip/hip_runtime.h>
#include <hip/hip_bf16.h>
#include <math.h>

#define HH 384
#define WW 384
#define HW (HH*WW)
#define BB 4
#define CC 8
#define NLAYERS 5
#define CGITERS 10
#define PI_F 3.14159265358979323846f

typedef __attribute__((ext_vector_type(8))) short short8;
typedef __attribute__((ext_vector_type(4))) float floatx4;

struct cf { float x, y; };
__device__ __forceinline__ cf cadd(cf a, cf b){ cf r; r.x=a.x+b.x; r.y=a.y+b.y; return r; }
__device__ __forceinline__ cf csub(cf a, cf b){ cf r; r.x=a.x-b.x; r.y=a.y-b.y; return r; }
__device__ __forceinline__ cf cmul(cf a, cf b){ cf r; r.x=a.x*b.x - a.y*b.y; r.y=a.x*b.y + a.y*b.x; return r; }
__device__ __forceinline__ cf shflxor(cf v, int m){ cf r; r.x = __shfl_xor(v.x, m); r.y = __shfl_xor(v.y, m); return r; }
__device__ __forceinline__ int brev7(int l){ return (int)(__brev((unsigned)l) >> 25); }
// LDS descramble pad: breaks stride-6/18 bank patterns (4/8-way -> ~2-way, free per m136)
__device__ __forceinline__ int padi(int i){ return i + (i >> 3); }

__device__ __forceinline__ void radix3(cf a0, cf a1, cf a2, float s3, cf y[3]) {
  float tx = a1.x + a2.x, ty_ = a1.y + a2.y;
  float ux = a1.x - a2.x, uy = a1.y - a2.y;
  y[0].x = a0.x + tx;              y[0].y = a0.y + ty_;
  y[1].x = a0.x - 0.5f*tx - s3*uy; y[1].y = a0.y - 0.5f*ty_ + s3*ux;
  y[2].x = a0.x - 0.5f*tx + s3*uy; y[2].y = a0.y - 0.5f*ty_ - s3*ux;
}

// 384-point DFT across one 64-lane wave. SIGN=-1 fwd, +1 inverse (no 1/N scale).
// Output: uA[k1] = X[k1 + 3*rev7(l)], uB[k1] = X[k1 + 3*(rev7(l)+1)].
template<int SIGN>
__device__ __forceinline__ void fft384_wave(int l, const cf v[6], cf uA[3], cf uB[3]) {
  const float s3 = SIGN * 0.8660254037844386f;
  radix3(v[0], v[2], v[4], s3, uA);
  radix3(v[1], v[3], v[5], s3, uB);
  const float base = SIGN * (2.0f * PI_F / 384.0f);
  float sA, cA; __sincosf(base * (float)l, &sA, &cA);
  cf wA1; wA1.x = cA; wA1.y = sA; cf wA2 = cmul(wA1, wA1);
  float sB, cB; __sincosf(base * (float)(l + 64), &sB, &cB);
  cf wB1; wB1.x = cB; wB1.y = sB; cf wB2 = cmul(wB1, wB1);
  uA[1] = cmul(uA[1], wA1); uA[2] = cmul(uA[2], wA2);
  uB[1] = cmul(uB[1], wB1); uB[2] = cmul(uB[2], wB2);
  {
    float s, c; __sincosf(SIGN * (PI_F/64.0f) * (float)l, &s, &c);
    cf w; w.x = c; w.y = s;
    #pragma unroll
    for (int k1 = 0; k1 < 3; ++k1) {
      cf a = uA[k1], b = uB[k1];
      uA[k1] = cadd(a, b);
      uB[k1] = cmul(csub(a, b), w);
    }
  }
  #pragma unroll
  for (int h = 32; h >= 1; h >>= 1) {
    const int j = l & (h - 1);
    float s, c; __sincosf(SIGN * PI_F * (float)j / (float)h, &s, &c);
    cf w; w.x = c; w.y = s;
    const bool up = (l & h) != 0;
    #pragma unroll
    for (int k1 = 0; k1 < 3; ++k1) {
      cf pa = shflxor(uA[k1], h);
      cf pb = shflxor(uB[k1], h);
      cf na = up ? cmul(csub(pa, uA[k1]), w) : cadd(uA[k1], pa);
      cf nb = up ? cmul(csub(pb, uB[k1]), w) : cadd(uB[k1], pb);
      uA[k1] = na; uB[k1] = nb;
    }
  }
}

// ---------------- conv kernels ----------------
// Activations in NHWC bf16: act[b][y][x][c], c=64 contiguous.

// repack ws_mid [7][64][64][3][3] fp32 -> wrep [7][9][64][64] bf16 (ci contiguous)
__global__ void repack_mid_k(const float* __restrict__ ws_mid, __hip_bfloat16* __restrict__ wrep) {
  const int idx = blockIdx.x * 256 + threadIdx.x;
  if (idx >= 7*9*64*64) return;
  const int ci = idx & 63, co = (idx >> 6) & 63, tap = (idx >> 12) % 9, i = idx / (9*4096);
  wrep[idx] = __float2bfloat16(ws_mid[(((size_t)i*64 + co)*64 + ci)*9 + tap]);
}

__global__ void __launch_bounds__(256) conv_in_k(const float* __restrict__ xin,
                                                 const float* __restrict__ w,
                                                 const float* __restrict__ bias,
                                                 __hip_bfloat16* __restrict__ out) {
  __shared__ float tile[2][340];
  const int tx = threadIdx.x & 31, ty = threadIdx.x >> 5;
  const int x0 = blockIdx.x * 32, y0 = blockIdx.y * 8, b = blockIdx.z;
  for (int e = threadIdx.x; e < 680; e += 256) {
    int ci = e / 340, rr = e % 340;
    int iy = y0 - 1 + rr / 34, ix = x0 - 1 + rr % 34;
    float v = 0.f;
    if (iy >= 0 && iy < HH && ix >= 0 && ix < WW)
      v = xin[(b*2 + ci)*HW + iy*WW + ix];
    tile[ci][rr] = v;
  }
  __syncthreads();
  float acc[64];
  #pragma unroll
  for (int co = 0; co < 64; ++co) acc[co] = bias[co];
  #pragma unroll
  for (int ci = 0; ci < 2; ++ci) {
    float v0 = tile[ci][ty*34+tx],     v1 = tile[ci][ty*34+tx+1],     v2 = tile[ci][ty*34+tx+2];
    float v3 = tile[ci][(ty+1)*34+tx], v4 = tile[ci][(ty+1)*34+tx+1], v5 = tile[ci][(ty+1)*34+tx+2];
    float v6 = tile[ci][(ty+2)*34+tx], v7 = tile[ci][(ty+2)*34+tx+1], v8 = tile[ci][(ty+2)*34+tx+2];
    #pragma unroll
    for (int co = 0; co < 64; ++co) {
      const float* wp = w + co*18 + ci*9;
      float a = acc[co];
      a = fmaf(v0, wp[0], a); a = fmaf(v1, wp[1], a); a = fmaf(v2, wp[2], a);
      a = fmaf(v3, wp[3], a); a = fmaf(v4, wp[4], a); a = fmaf(v5, wp[5], a);
      a = fmaf(v6, wp[6], a); a = fmaf(v7, wp[7], a); a = fmaf(v8, wp[8], a);
      acc[co] = a;
    }
  }
  const size_t obase = ((size_t)(b*HH + y0 + ty)*WW + (x0 + tx))*64;
  #pragma unroll
  for (int s = 0; s < 8; ++s) {
    uint4 u;
    __hip_bfloat16* hp = (__hip_bfloat16*)&u;
    #pragma unroll
    for (int j = 0; j < 8; ++j) hp[j] = __float2bfloat16(acc[s*8 + j]);
    *(uint4*)(out + obase + s*8) = u;
  }
}

// MFMA implicit-GEMM mid conv. A-tile in LDS (one sync); B-frags straight from
// global (L1-resident, 8KB/tap) with 1-tap software prefetch.
__global__ void __launch_bounds__(256) conv_mid_mfma_k(
    const __hip_bfloat16* __restrict__ in,    // NHWC
    const __hip_bfloat16* __restrict__ wrep,  // [9][64][64] bf16
    const float* __restrict__ bias,
    __hip_bfloat16* __restrict__ out, int relu) {
  __shared__ __hip_bfloat16 atile[10*34*72];  // ch padded 64->72: conflict-free b128 reads
  const int tid = threadIdx.x;
  const int l = tid & 63, wv = tid >> 6;
  const int x0 = blockIdx.x * 32, y0 = blockIdx.y * 8, b = blockIdx.z;

  for (int e = tid; e < 340*8; e += 256) {
    int p = e >> 3, s = e & 7;
    int iy = y0 - 1 + p / 34, ix = x0 - 1 + p % 34;
    uint4 v = make_uint4(0u, 0u, 0u, 0u);
    if (iy >= 0 && iy < HH && ix >= 0 && ix < WW)
      v = *(const uint4*)(in + ((size_t)(b*HH + iy)*WW + ix)*64 + s*8);
    *(uint4*)(&atile[p*72 + s*8]) = v;
  }

  floatx4 acc[4][4];
  #pragma unroll
  for (int mt = 0; mt < 4; ++mt)
    #pragma unroll
    for (int nt = 0; nt < 4; ++nt)
      acc[mt][nt] = (floatx4){0.f, 0.f, 0.f, 0.f};

  const int kseg = l >> 4;
  const int lr = l & 15;

  // prefetch tap 0 weights while atile staging is in flight
  const __hip_bfloat16* wlane = wrep + lr*64 + kseg*8;
  short8 bf[4][2];
  #pragma unroll
  for (int nt = 0; nt < 4; ++nt) {
    bf[nt][0] = *(const short8*)(wlane + nt*1024);
    bf[nt][1] = *(const short8*)(wlane + nt*1024 + 32);
  }

  __syncthreads();

  #pragma unroll 1
  for (int tap = 0; tap < 9; ++tap) {
    short8 bfn[4][2];
    if (tap < 8) {
      const __hip_bfloat16* wn = wlane + (tap + 1)*4096;
      #pragma unroll
      for (int nt = 0; nt < 4; ++nt) {
        bfn[nt][0] = *(const short8*)(wn + nt*1024);
        bfn[nt][1] = *(const short8*)(wn + nt*1024 + 32);
      }
    }
    const int dy = tap / 3, dx = tap - dy*3;
    short8 af[4][2];
    #pragma unroll
    for (int mt = 0; mt < 4; ++mt) {
      const int ry = 2*wv + (mt >> 1) + dy;
      const int px = (mt & 1)*16 + lr + dx;
      const __hip_bfloat16* ap = &atile[(ry*34 + px)*72 + kseg*8];
      af[mt][0] = *(const short8*)(ap);
      af[mt][1] = *(const short8*)(ap + 32);
    }
    #pragma unroll
    for (int mt = 0; mt < 4; ++mt)
      #pragma unroll
      for (int nt = 0; nt < 4; ++nt) {
        acc[mt][nt] = __builtin_amdgcn_mfma_f32_16x16x32_bf16(af[mt][0], bf[nt][0], acc[mt][nt], 0, 0, 0);
        acc[mt][nt] = __builtin_amdgcn_mfma_f32_16x16x32_bf16(af[mt][1], bf[nt][1], acc[mt][nt], 0, 0, 0);
      }
    if (tap < 8) {
      #pragma unroll
      for (int nt = 0; nt < 4; ++nt) { bf[nt][0] = bfn[nt][0]; bf[nt][1] = bfn[nt][1]; }
    }
  }

  #pragma unroll
  for (int nt = 0; nt < 4; ++nt) {
    const float bv = bias[nt*16 + lr];
    #pragma unroll
    for (int mt = 0; mt < 4; ++mt) {
      const int ry = 2*wv + (mt >> 1);
      const int xb = (mt & 1)*16 + kseg*4;
      #pragma unroll
      for (int rr = 0; rr < 4; ++rr) {
        float v = acc[mt][nt][rr] + bv;
        if (relu) v = fmaxf(v, 0.f);
        out[((size_t)(b*HH + y0 + ry)*WW + (x0 + xb + rr))*64 + nt*16 + lr] = __float2bfloat16(v);
      }
    }
  }
}

// conv_out (co=2) fused with CG init; reads NHWC bf16
__global__ void __launch_bounds__(256) conv_out_k(const __hip_bfloat16* __restrict__ in,
                                                  const float* __restrict__ w,
                                                  const float* __restrict__ bias,
                                                  const float* __restrict__ xcur,
                                                  const float* __restrict__ under,
                                                  const float* __restrict__ lam,
                                                  cf* __restrict__ r, cf* __restrict__ p,
                                                  cf* __restrict__ xc, float* __restrict__ rtr0) {
  __shared__ float wl[2*64*9];
  __shared__ float wsum[4];
  const int tx = threadIdx.x & 31, ty = threadIdx.x >> 5;
  const int x0 = blockIdx.x * 32, y0 = blockIdx.y * 8, b = blockIdx.z;
  for (int e = threadIdx.x; e < 2*64*9; e += 256) wl[e] = w[e];
  __syncthreads();
  const int y = y0 + ty, x = x0 + tx;
  float a0 = bias[0], a1 = bias[1];
  for (int tap = 0; tap < 9; ++tap) {
    const int iy = y + tap/3 - 1, ix = x + tap%3 - 1;
    if (iy < 0 || iy >= HH || ix < 0 || ix >= WW) continue;
    const __hip_bfloat16* pp = in + ((size_t)(b*HH + iy)*WW + ix)*64;
    #pragma unroll
    for (int s = 0; s < 8; ++s) {
      uint4 v = *(const uint4*)(pp + s*8);
      const __hip_bfloat16* hv = (const __hip_bfloat16*)&v;
      #pragma unroll
      for (int j = 0; j < 8; ++j) {
        const float f = __bfloat162float(hv[j]);
        a0 = fmaf(f, wl[(s*8 + j)*9 + tap], a0);
        a1 = fmaf(f, wl[(64 + s*8 + j)*9 + tap], a1);
      }
    }
  }
  const float lamv = lam[0];
  const int idx2 = y*WW + x;
  float xv0 = xcur[b*2*HW + idx2],  xv1 = xcur[b*2*HW + HW + idx2];
  float u0  = under[b*2*HW + idx2], u1  = under[b*2*HW + HW + idx2];
  float r0 = u0 + lamv * (xv0 + a0);
  float r1 = u1 + lamv * (xv1 + a1);
  const int cidx = b*HW + idx2;
  cf vv; vv.x = r0; vv.y = r1;
  r[cidx] = vv; p[cidx] = vv;
  cf zz; zz.x = 0.f; zz.y = 0.f; xc[cidx] = zz;
  float partial = r0*r0 + r1*r1;
  for (int off = 32; off; off >>= 1) partial += __shfl_down(partial, off);
  const int l = threadIdx.x & 63, wvid = threadIdx.x >> 6;
  if (l == 0) wsum[wvid] = partial;
  __syncthreads();
  if (threadIdx.x == 0) atomicAdd(&rtr0[b], wsum[0]+wsum[1]+wsum[2]+wsum[3]);
}

// ---------------- CG / FFT kernels ----------------

// rows, one coil per block (grid: H/4 x CC x BB). Folds p-update (upd2):
// it>0: pv = r + beta*p_prev, written to pnext by the c==0 block only.
__global__ void __launch_bounds__(256) pass_a_k(const cf* __restrict__ pprev,
                                                const cf* __restrict__ rres,
                                                cf* __restrict__ pnext,
                                                const cf* __restrict__ csm,
                                                cf* __restrict__ t,
                                                const float* __restrict__ sc, int it,
                                                float* __restrict__ pAp) {
  __shared__ cf rowbuf[4][434];
  const int l = threadIdx.x & 63, wv = threadIdx.x >> 6;
  const int y = blockIdx.x * 4 + wv;
  const int c = blockIdx.y, b = blockIdx.z;
  if (blockIdx.x == 0 && c == 0 && b == 0 && threadIdx.x < BB) pAp[threadIdx.x] = 0.f;
  const cf* prow = pprev + b*HW + y*WW;
  cf pv[6];
  if (it == 0) {
    #pragma unroll
    for (int m = 0; m < 6; ++m) pv[m] = prow[l + 64*m];
  } else {
    const float beta = sc[4 + it*4 + b] / sc[4 + (it-1)*4 + b];
    const cf* rrow = rres + b*HW + y*WW;
    #pragma unroll
    for (int m = 0; m < 6; ++m) {
      cf rv = rrow[l + 64*m], po = prow[l + 64*m];
      pv[m].x = rv.x + beta*po.x; pv[m].y = rv.y + beta*po.y;
    }
    if (c == 0) {
      cf* pn = pnext + b*HW + y*WW;
      #pragma unroll
      for (int m = 0; m < 6; ++m) pn[l + 64*m] = pv[m];
    }
  }
  const cf* crow = csm + (b*CC + c)*HW + y*WW;
  cf v[6];
  #pragma unroll
  for (int m = 0; m < 6; ++m) v[m] = cmul(crow[l + 64*m], pv[m]);
  cf uA[3], uB[3];
  fft384_wave<-1>(l, v, uA, uB);
  const int R3 = 3 * brev7(l);
  #pragma unroll
  for (int k1 = 0; k1 < 3; ++k1) { rowbuf[wv][padi(k1 + R3)] = uA[k1]; rowbuf[wv][padi(k1 + R3 + 3)] = uB[k1]; }
  __syncthreads();
  cf* trow = t + (b*CC + c)*HW + y*WW;
  #pragma unroll
  for (int m = 0; m < 6; ++m) trow[l + 64*m] = rowbuf[wv][padi(l + 64*m)];
}

__global__ void __launch_bounds__(256) pass_b_k(cf* __restrict__ t, const float* __restrict__ mask) {
  __shared__ cf tile[431*9];
  const int b = blockIdx.z, c = blockIdx.y, x0 = blockIdx.x * 8;
  cf* base = t + (b*CC + c)*HW;
  for (int e = threadIdx.x; e < 3072; e += 256) {
    int y = e >> 3, xx = e & 7;
    tile[padi(y)*9 + xx] = base[y*WW + x0 + xx];
  }
  __syncthreads();
  const int l = threadIdx.x & 63, wv = threadIdx.x >> 6;
  const int R3 = 3 * brev7(l);
  for (int rep = 0; rep < 2; ++rep) {
    const int xx = wv*2 + rep, x = x0 + xx;
    cf v[6];
    #pragma unroll
    for (int m = 0; m < 6; ++m) v[m] = tile[padi(l + 64*m)*9 + xx];
    cf uA[3], uB[3];
    fft384_wave<-1>(l, v, uA, uB);
    const float* mrow = mask + b*HW + x;
    #pragma unroll
    for (int k1 = 0; k1 < 3; ++k1) {
      float mA = mrow[(k1 + R3)*WW], mB = mrow[(k1 + R3 + 3)*WW];
      uA[k1].x *= mA; uA[k1].y *= mA; uB[k1].x *= mB; uB[k1].y *= mB;
    }
    __syncthreads();
    #pragma unroll
    for (int k1 = 0; k1 < 3; ++k1) { tile[padi(k1 + R3)*9 + xx] = uA[k1]; tile[padi(k1 + R3 + 3)*9 + xx] = uB[k1]; }
    __syncthreads();
    #pragma unroll
    for (int m = 0; m < 6; ++m) v[m] = tile[padi(l + 64*m)*9 + xx];
    fft384_wave<1>(l, v, uA, uB);
    const float s = 1.0f / 384.0f;
    #pragma unroll
    for (int k1 = 0; k1 < 3; ++k1) {
      uA[k1].x *= s; uA[k1].y *= s; uB[k1].x *= s; uB[k1].y *= s;
      tile[padi(k1 + R3)*9 + xx] = uA[k1]; tile[padi(k1 + R3 + 3)*9 + xx] = uB[k1];
    }
    __syncthreads();
  }
  for (int e = threadIdx.x; e < 3072; e += 256) {
    int y = e >> 3, xx = e & 7;
    base[y*WW + x0 + xx] = tile[padi(y)*9 + xx];
  }
}

__global__ void __launch_bounds__(256) pass_c_k(const cf* __restrict__ t, const cf* __restrict__ csm,
                                                const cf* __restrict__ p, cf* __restrict__ Ap,
                                                const float* __restrict__ lam, float* __restrict__ pAp) {
  __shared__ cf rowbuf[4][434];
  __shared__ float wsum[4];
  const int l = threadIdx.x & 63, wv = threadIdx.x >> 6;
  const int y = blockIdx.x * 4 + wv, b = blockIdx.y;
  const int R3 = 3 * brev7(l);
  cf acc[6] = {};
  for (int c = 0; c < CC; ++c) {
    const cf* trow = t + (b*CC + c)*HW + y*WW;
    cf v[6];
    #pragma unroll
    for (int m = 0; m < 6; ++m) v[m] = trow[l + 64*m];
    cf uA[3], uB[3];
    fft384_wave<1>(l, v, uA, uB);
    __syncthreads();
    #pragma unroll
    for (int k1 = 0; k1 < 3; ++k1) { rowbuf[wv][padi(k1 + R3)] = uA[k1]; rowbuf[wv][padi(k1 + R3 + 3)] = uB[k1]; }
    __syncthreads();
    const cf* crow = csm + (b*CC + c)*HW + y*WW;
    #pragma unroll
    for (int m = 0; m < 6; ++m) {
      cf cs = crow[l + 64*m];
      cf wz = rowbuf[wv][padi(l + 64*m)];
      acc[m].x += cs.x*wz.x + cs.y*wz.y;
      acc[m].y += cs.x*wz.y - cs.y*wz.x;
    }
  }
  const float lamv = lam[0];
  const float sc384 = 1.0f / 384.0f;
  const cf* prow = p + b*HW + y*WW;
  cf* aprow = Ap + b*HW + y*WW;
  float partial = 0.f;
  #pragma unroll
  for (int m = 0; m < 6; ++m) {
    cf pv = prow[l + 64*m];
    cf ap; ap.x = acc[m].x*sc384 + lamv*pv.x; ap.y = acc[m].y*sc384 + lamv*pv.y;
    aprow[l + 64*m] = ap;
    partial += pv.x*ap.x + pv.y*ap.y;
  }
  for (int off = 32; off; off >>= 1) partial += __shfl_down(partial, off);
  if (l == 0) wsum[wv] = partial;
  __syncthreads();
  if (threadIdx.x == 0) atomicAdd(&pAp[b], wsum[0]+wsum[1]+wsum[2]+wsum[3]);
}

__global__ void __launch_bounds__(256) upd1_k(cf* __restrict__ x, cf* __restrict__ r,
                                              const cf* __restrict__ p, const cf* __restrict__ Ap,
                                              const float* __restrict__ rtr_cur,
                                              const float* __restrict__ pAp,
                                              float* __restrict__ rtr_next) {
  __shared__ float wsum[4];
  const int idx = blockIdx.x * 256 + threadIdx.x;
  const int b = idx / HW;
  const float alpha = rtr_cur[b] / pAp[b];
  cf pv = p[idx], apv = Ap[idx];
  cf xv = x[idx]; xv.x += alpha*pv.x; xv.y += alpha*pv.y; x[idx] = xv;
  cf rv = r[idx]; rv.x -= alpha*apv.x; rv.y -= alpha*apv.y; r[idx] = rv;
  float partial = rv.x*rv.x + rv.y*rv.y;
  for (int off = 32; off; off >>= 1) partial += __shfl_down(partial, off);
  const int l = threadIdx.x & 63, wv = threadIdx.x >> 6;
  if (l == 0) wsum[wv] = partial;
  __syncthreads();
  if (threadIdx.x == 0) atomicAdd(&rtr_next[b], wsum[0]+wsum[1]+wsum[2]+wsum[3]);
}

__global__ void __launch_bounds__(256) store_x_k(const cf* __restrict__ xc, float* __restrict__ out) {
  const int idx = blockIdx.x * 256 + threadIdx.x;
  const int b = idx / HW;
  const int rem = idx - b*HW;
  cf v = xc[idx];
  out[b*2*HW + rem] = v.x;
  out[b*2*HW + HW + rem] = v.y;
}

__global__ void zero_sc_k(float* sc) { if (threadIdx.x < 64) sc[threadIdx.x] = 0.f; }

extern "C" void kernel_launch(void* const* d_in, const int* in_sizes, int n_in,
                              void* d_out, int out_size, void* d_ws, size_t ws_size,
                              hipStream_t stream) {
  (void)in_sizes; (void)n_in; (void)out_size; (void)ws_size;
  const float* under  = (const float*)d_in[0];
  const cf*    csm    = (const cf*)d_in[1];
  const float* mask   = (const float*)d_in[2];
  const float* lam    = (const float*)d_in[3];
  const float* w_in   = (const float*)d_in[4];
  const float* b_in   = (const float*)d_in[5];
  const float* ws_mid = (const float*)d_in[6];
  const float* bs_mid = (const float*)d_in[7];
  const float* w_out  = (const float*)d_in[8];
  const float* b_out  = (const float*)d_in[9];
  float* xcur = (float*)d_out;

  char* bws = (char*)d_ws;
  size_t off = 0;
  auto carve = [&](size_t bytes) { char* pp = bws + off; off += (bytes + 255) & ~(size_t)255; return (void*)pp; };
  __hip_bfloat16* actA = (__hip_bfloat16*)carve((size_t)BB*64*HW*2);
  __hip_bfloat16* actB = (__hip_bfloat16*)carve((size_t)BB*64*HW*2);
  cf* t     = (cf*)carve((size_t)BB*CC*HW*8);
  cf* r     = (cf*)carve((size_t)BB*HW*8);
  cf* pbuf0 = (cf*)carve((size_t)BB*HW*8);
  cf* pbuf1 = (cf*)carve((size_t)BB*HW*8);
  cf* xc    = (cf*)carve((size_t)BB*HW*8);
  cf* Ap    = (cf*)carve((size_t)BB*HW*8);
  float* sc = (float*)carve(256*4);
  __hip_bfloat16* wrep = (__hip_bfloat16*)carve((size_t)7*9*64*64*2);

  hipMemcpyAsync(xcur, under, (size_t)BB*2*HW*sizeof(float), hipMemcpyDeviceToDevice, stream);

  repack_mid_k<<<(7*9*64*64 + 255)/256, 256, 0, stream>>>(ws_mid, wrep);

  dim3 cgrid(WW/32, HH/8, BB);
  dim3 agrid(HH/4, CC, BB);
  dim3 cgrid2(HH/4, BB);
  dim3 colgrid(WW/8, CC, BB);
  const int egrid = BB*HW/256;

  __hip_bfloat16* bufs[2] = { actA, actB };
  cf* pbufs[2] = { pbuf0, pbuf1 };

  for (int layer = 0; layer < NLAYERS; ++layer) {
    zero_sc_k<<<1, 64, 0, stream>>>(sc);
    conv_in_k<<<cgrid, 256, 0, stream>>>(xcur, w_in, b_in, bufs[0]);
    for (int i = 0; i < 7; ++i) {
      conv_mid_mfma_k<<<cgrid, 256, 0, stream>>>(bufs[i & 1], wrep + (size_t)i*9*4096,
                                                 bs_mid + i*64, bufs[(i + 1) & 1], (i % 2 == 0) ? 1 : 0);
    }
    conv_out_k<<<cgrid, 256, 0, stream>>>(bufs[1], w_out, b_out, xcur, under, lam,
                                          r, pbuf0, xc, sc + 4);
    for (int it = 0; it < CGITERS; ++it) {
      cf* pprev = (it == 0) ? pbuf0 : pbufs[(it - 1) & 1];
      cf* puse  = pbufs[it & 1];
      pass_a_k<<<agrid, 256, 0, stream>>>(pprev, r, puse, csm, t, sc, it, sc);
      pass_b_k<<<colgrid, 256, 0, stream>>>(t, mask);
      pass_c_k<<<cgrid2, 256, 0, stream>>>(t, csm, puse, Ap, lam, sc);
      upd1_k<<<egrid, 256, 0, stream>>>(xc, r, puse, Ap, sc + 4 + it*4, sc, sc + 4 + (it+1)*4);
    }
    store_x_k<<<egrid, 256, 0, stream>>>(xc, xcur);
  }
}

// Round 4
// 15081.589 us; speedup vs baseline: 2.8856x; 1.0185x over previous
//
#include <hip/hip_runtime.h>
#include <hip/hip_bf16.h>
#include <math.h>

#define HH 384
#define WW 384
#define HW (HH*WW)
#define BB 4
#define CC 8
#define NLAYERS 5
#define CGITERS 10
#define PI_F 3.14159265358979323846f

typedef __attribute__((ext_vector_type(8))) short short8;
typedef __attribute__((ext_vector_type(4))) float floatx4;

struct cf { float x, y; };
__device__ __forceinline__ cf cadd(cf a, cf b){ cf r; r.x=a.x+b.x; r.y=a.y+b.y; return r; }
__device__ __forceinline__ cf csub(cf a, cf b){ cf r; r.x=a.x-b.x; r.y=a.y-b.y; return r; }
__device__ __forceinline__ cf cmul(cf a, cf b){ cf r; r.x=a.x*b.x - a.y*b.y; r.y=a.x*b.y + a.y*b.x; return r; }
__device__ __forceinline__ cf shflxor(cf v, int m){ cf r; r.x = __shfl_xor(v.x, m); r.y = __shfl_xor(v.y, m); return r; }
__device__ __forceinline__ int brev7(int l){ return (int)(__brev((unsigned)l) >> 25); }
// LDS descramble pad: breaks stride-6/18 bank patterns
__device__ __forceinline__ int padi(int i){ return i + (i >> 3); }

__device__ __forceinline__ void radix3(cf a0, cf a1, cf a2, float s3, cf y[3]) {
  float tx = a1.x + a2.x, ty_ = a1.y + a2.y;
  float ux = a1.x - a2.x, uy = a1.y - a2.y;
  y[0].x = a0.x + tx;              y[0].y = a0.y + ty_;
  y[1].x = a0.x - 0.5f*tx - s3*uy; y[1].y = a0.y - 0.5f*ty_ + s3*ux;
  y[2].x = a0.x - 0.5f*tx + s3*uy; y[2].y = a0.y - 0.5f*ty_ - s3*ux;
}

// 384-point DFT across one 64-lane wave. SIGN=-1 fwd, +1 inverse (no 1/N scale).
// Output: uA[k1] = X[k1 + 3*rev7(l)], uB[k1] = X[k1 + 3*(rev7(l)+1)].
template<int SIGN>
__device__ __forceinline__ void fft384_wave(int l, const cf v[6], cf uA[3], cf uB[3]) {
  const float s3 = SIGN * 0.8660254037844386f;
  radix3(v[0], v[2], v[4], s3, uA);
  radix3(v[1], v[3], v[5], s3, uB);
  const float base = SIGN * (2.0f * PI_F / 384.0f);
  float sA, cA; __sincosf(base * (float)l, &sA, &cA);
  cf wA1; wA1.x = cA; wA1.y = sA; cf wA2 = cmul(wA1, wA1);
  float sB, cB; __sincosf(base * (float)(l + 64), &sB, &cB);
  cf wB1; wB1.x = cB; wB1.y = sB; cf wB2 = cmul(wB1, wB1);
  uA[1] = cmul(uA[1], wA1); uA[2] = cmul(uA[2], wA2);
  uB[1] = cmul(uB[1], wB1); uB[2] = cmul(uB[2], wB2);
  {
    float s, c; __sincosf(SIGN * (PI_F/64.0f) * (float)l, &s, &c);
    cf w; w.x = c; w.y = s;
    #pragma unroll
    for (int k1 = 0; k1 < 3; ++k1) {
      cf a = uA[k1], b = uB[k1];
      uA[k1] = cadd(a, b);
      uB[k1] = cmul(csub(a, b), w);
    }
  }
  #pragma unroll
  for (int h = 32; h >= 1; h >>= 1) {
    const int j = l & (h - 1);
    float s, c; __sincosf(SIGN * PI_F * (float)j / (float)h, &s, &c);
    cf w; w.x = c; w.y = s;
    const bool up = (l & h) != 0;
    #pragma unroll
    for (int k1 = 0; k1 < 3; ++k1) {
      cf pa = shflxor(uA[k1], h);
      cf pb = shflxor(uB[k1], h);
      cf na = up ? cmul(csub(pa, uA[k1]), w) : cadd(uA[k1], pa);
      cf nb = up ? cmul(csub(pb, uB[k1]), w) : cadd(uB[k1], pb);
      uA[k1] = na; uB[k1] = nb;
    }
  }
}

// ---------------- conv kernels ----------------
// Activations in NHWC bf16: act[b][y][x][c], c=64 contiguous.

// repack ws_mid [7][64][64][3][3] fp32 -> wrep [7][9][64][64] bf16 (ci contiguous)
__global__ void repack_mid_k(const float* __restrict__ ws_mid, __hip_bfloat16* __restrict__ wrep) {
  const int idx = blockIdx.x * 256 + threadIdx.x;
  if (idx >= 7*9*64*64) return;
  const int ci = idx & 63, co = (idx >> 6) & 63, tap = (idx >> 12) % 9, i = idx / (9*4096);
  wrep[idx] = __float2bfloat16(ws_mid[(((size_t)i*64 + co)*64 + ci)*9 + tap]);
}

__global__ void __launch_bounds__(256) conv_in_k(const float* __restrict__ xin,
                                                 const float* __restrict__ w,
                                                 const float* __restrict__ bias,
                                                 __hip_bfloat16* __restrict__ out) {
  __shared__ float tile[2][340];
  const int tx = threadIdx.x & 31, ty = threadIdx.x >> 5;
  const int x0 = blockIdx.x * 32, y0 = blockIdx.y * 8, b = blockIdx.z;
  for (int e = threadIdx.x; e < 680; e += 256) {
    int ci = e / 340, rr = e % 340;
    int iy = y0 - 1 + rr / 34, ix = x0 - 1 + rr % 34;
    float v = 0.f;
    if (iy >= 0 && iy < HH && ix >= 0 && ix < WW)
      v = xin[(b*2 + ci)*HW + iy*WW + ix];
    tile[ci][rr] = v;
  }
  __syncthreads();
  float acc[64];
  #pragma unroll
  for (int co = 0; co < 64; ++co) acc[co] = bias[co];
  #pragma unroll
  for (int ci = 0; ci < 2; ++ci) {
    float v0 = tile[ci][ty*34+tx],     v1 = tile[ci][ty*34+tx+1],     v2 = tile[ci][ty*34+tx+2];
    float v3 = tile[ci][(ty+1)*34+tx], v4 = tile[ci][(ty+1)*34+tx+1], v5 = tile[ci][(ty+1)*34+tx+2];
    float v6 = tile[ci][(ty+2)*34+tx], v7 = tile[ci][(ty+2)*34+tx+1], v8 = tile[ci][(ty+2)*34+tx+2];
    #pragma unroll
    for (int co = 0; co < 64; ++co) {
      const float* wp = w + co*18 + ci*9;
      float a = acc[co];
      a = fmaf(v0, wp[0], a); a = fmaf(v1, wp[1], a); a = fmaf(v2, wp[2], a);
      a = fmaf(v3, wp[3], a); a = fmaf(v4, wp[4], a); a = fmaf(v5, wp[5], a);
      a = fmaf(v6, wp[6], a); a = fmaf(v7, wp[7], a); a = fmaf(v8, wp[8], a);
      acc[co] = a;
    }
  }
  const size_t obase = ((size_t)(b*HH + y0 + ty)*WW + (x0 + tx))*64;
  #pragma unroll
  for (int s = 0; s < 8; ++s) {
    uint4 u;
    __hip_bfloat16* hp = (__hip_bfloat16*)&u;
    #pragma unroll
    for (int j = 0; j < 8; ++j) hp[j] = __float2bfloat16(acc[s*8 + j]);
    *(uint4*)(out + obase + s*8) = u;
  }
}

// MFMA implicit-GEMM mid conv. A-tile in LDS; B-frags from global (L1-resident)
// with 1-tap prefetch. Epilogue: LDS transpose (reusing atile) -> coalesced
// 16-B stores (the 64x global_store_short pattern was the round-2/3 bottleneck).
__global__ void __launch_bounds__(256) conv_mid_mfma_k(
    const __hip_bfloat16* __restrict__ in,    // NHWC
    const __hip_bfloat16* __restrict__ wrep,  // [9][64][64] bf16
    const float* __restrict__ bias,
    __hip_bfloat16* __restrict__ out, int relu) {
  __shared__ __hip_bfloat16 atile[10*34*72];  // ch padded 64->72
  const int tid = threadIdx.x;
  const int l = tid & 63, wv = tid >> 6;
  const int x0 = blockIdx.x * 32, y0 = blockIdx.y * 8, b = blockIdx.z;

  for (int e = tid; e < 340*8; e += 256) {
    int p = e >> 3, s = e & 7;
    int iy = y0 - 1 + p / 34, ix = x0 - 1 + p % 34;
    uint4 v = make_uint4(0u, 0u, 0u, 0u);
    if (iy >= 0 && iy < HH && ix >= 0 && ix < WW)
      v = *(const uint4*)(in + ((size_t)(b*HH + iy)*WW + ix)*64 + s*8);
    *(uint4*)(&atile[p*72 + s*8]) = v;
  }

  floatx4 acc[4][4];
  #pragma unroll
  for (int mt = 0; mt < 4; ++mt)
    #pragma unroll
    for (int nt = 0; nt < 4; ++nt)
      acc[mt][nt] = (floatx4){0.f, 0.f, 0.f, 0.f};

  const int kseg = l >> 4;
  const int lr = l & 15;

  // prefetch tap 0 weights while atile staging is in flight
  const __hip_bfloat16* wlane = wrep + lr*64 + kseg*8;
  short8 bf[4][2];
  #pragma unroll
  for (int nt = 0; nt < 4; ++nt) {
    bf[nt][0] = *(const short8*)(wlane + nt*1024);
    bf[nt][1] = *(const short8*)(wlane + nt*1024 + 32);
  }

  __syncthreads();

  #pragma unroll 1
  for (int tap = 0; tap < 9; ++tap) {
    short8 bfn[4][2];
    if (tap < 8) {
      const __hip_bfloat16* wn = wlane + (tap + 1)*4096;
      #pragma unroll
      for (int nt = 0; nt < 4; ++nt) {
        bfn[nt][0] = *(const short8*)(wn + nt*1024);
        bfn[nt][1] = *(const short8*)(wn + nt*1024 + 32);
      }
    }
    const int dy = tap / 3, dx = tap - dy*3;
    short8 af[4][2];
    #pragma unroll
    for (int mt = 0; mt < 4; ++mt) {
      const int ry = 2*wv + (mt >> 1) + dy;
      const int px = (mt & 1)*16 + lr + dx;
      const __hip_bfloat16* ap = &atile[(ry*34 + px)*72 + kseg*8];
      af[mt][0] = *(const short8*)(ap);
      af[mt][1] = *(const short8*)(ap + 32);
    }
    #pragma unroll
    for (int mt = 0; mt < 4; ++mt)
      #pragma unroll
      for (int nt = 0; nt < 4; ++nt) {
        acc[mt][nt] = __builtin_amdgcn_mfma_f32_16x16x32_bf16(af[mt][0], bf[nt][0], acc[mt][nt], 0, 0, 0);
        acc[mt][nt] = __builtin_amdgcn_mfma_f32_16x16x32_bf16(af[mt][1], bf[nt][1], acc[mt][nt], 0, 0, 0);
      }
    if (tap < 8) {
      #pragma unroll
      for (int nt = 0; nt < 4; ++nt) { bf[nt][0] = bfn[nt][0]; bf[nt][1] = bfn[nt][1]; }
    }
  }

  // ---- LDS-transpose epilogue ----
  __syncthreads();                      // all atile A-reads done; safe to reuse
  __hip_bfloat16* otile = atile;        // layout [256 pixels][72 pad]
  #pragma unroll
  for (int mt = 0; mt < 4; ++mt) {
    const int row = 2*wv + (mt >> 1);
    #pragma unroll
    for (int nt = 0; nt < 4; ++nt) {
      const int ch = nt*16 + lr;
      const float bv = bias[ch];
      #pragma unroll
      for (int rr = 0; rr < 4; ++rr) {
        const int px = (mt & 1)*16 + kseg*4 + rr;
        float v = acc[mt][nt][rr] + bv;
        if (relu) v = fmaxf(v, 0.f);
        otile[(row*32 + px)*72 + ch] = __float2bfloat16(v);
      }
    }
  }
  __syncthreads();
  #pragma unroll
  for (int iter = 0; iter < 8; ++iter) {
    const int p = iter*32 + (tid >> 3), s = tid & 7;
    const int row = p >> 5, px = p & 31;
    uint4 v = *(const uint4*)(&otile[p*72 + s*8]);
    *(uint4*)(out + ((size_t)(b*HH + y0 + row)*WW + (x0 + px))*64 + s*8) = v;
  }
}

// conv_out (co=2) fused with CG init; reads NHWC bf16
__global__ void __launch_bounds__(256) conv_out_k(const __hip_bfloat16* __restrict__ in,
                                                  const float* __restrict__ w,
                                                  const float* __restrict__ bias,
                                                  const float* __restrict__ xcur,
                                                  const float* __restrict__ under,
                                                  const float* __restrict__ lam,
                                                  cf* __restrict__ r, cf* __restrict__ p,
                                                  cf* __restrict__ xc, float* __restrict__ rtr0) {
  __shared__ float wl[2*64*9];
  __shared__ float wsum[4];
  const int tx = threadIdx.x & 31, ty = threadIdx.x >> 5;
  const int x0 = blockIdx.x * 32, y0 = blockIdx.y * 8, b = blockIdx.z;
  for (int e = threadIdx.x; e < 2*64*9; e += 256) wl[e] = w[e];
  __syncthreads();
  const int y = y0 + ty, x = x0 + tx;
  float a0 = bias[0], a1 = bias[1];
  for (int tap = 0; tap < 9; ++tap) {
    const int iy = y + tap/3 - 1, ix = x + tap%3 - 1;
    if (iy < 0 || iy >= HH || ix < 0 || ix >= WW) continue;
    const __hip_bfloat16* pp = in + ((size_t)(b*HH + iy)*WW + ix)*64;
    #pragma unroll
    for (int s = 0; s < 8; ++s) {
      uint4 v = *(const uint4*)(pp + s*8);
      const __hip_bfloat16* hv = (const __hip_bfloat16*)&v;
      #pragma unroll
      for (int j = 0; j < 8; ++j) {
        const float f = __bfloat162float(hv[j]);
        a0 = fmaf(f, wl[(s*8 + j)*9 + tap], a0);
        a1 = fmaf(f, wl[(64 + s*8 + j)*9 + tap], a1);
      }
    }
  }
  const float lamv = lam[0];
  const int idx2 = y*WW + x;
  float xv0 = xcur[b*2*HW + idx2],  xv1 = xcur[b*2*HW + HW + idx2];
  float u0  = under[b*2*HW + idx2], u1  = under[b*2*HW + HW + idx2];
  float r0 = u0 + lamv * (xv0 + a0);
  float r1 = u1 + lamv * (xv1 + a1);
  const int cidx = b*HW + idx2;
  cf vv; vv.x = r0; vv.y = r1;
  r[cidx] = vv; p[cidx] = vv;
  cf zz; zz.x = 0.f; zz.y = 0.f; xc[cidx] = zz;
  float partial = r0*r0 + r1*r1;
  for (int off = 32; off; off >>= 1) partial += __shfl_down(partial, off);
  const int l = threadIdx.x & 63, wvid = threadIdx.x >> 6;
  if (l == 0) wsum[wvid] = partial;
  __syncthreads();
  if (threadIdx.x == 0) atomicAdd(&rtr0[b], wsum[0]+wsum[1]+wsum[2]+wsum[3]);
}

// ---------------- CG / FFT kernels ----------------

// rows, one coil per block (grid: H/4 x CC x BB). Folds p-update:
// it>0: pv = r + beta*p_prev, written to pnext by the c==0 block only.
__global__ void __launch_bounds__(256) pass_a_k(const cf* __restrict__ pprev,
                                                const cf* __restrict__ rres,
                                                cf* __restrict__ pnext,
                                                const cf* __restrict__ csm,
                                                cf* __restrict__ t,
                                                const float* __restrict__ sc, int it,
                                                float* __restrict__ pAp) {
  __shared__ cf rowbuf[4][434];
  const int l = threadIdx.x & 63, wv = threadIdx.x >> 6;
  const int y = blockIdx.x * 4 + wv;
  const int c = blockIdx.y, b = blockIdx.z;
  if (blockIdx.x == 0 && c == 0 && b == 0 && threadIdx.x < BB) pAp[threadIdx.x] = 0.f;
  const cf* prow = pprev + b*HW + y*WW;
  cf pv[6];
  if (it == 0) {
    #pragma unroll
    for (int m = 0; m < 6; ++m) pv[m] = prow[l + 64*m];
  } else {
    const float beta = sc[4 + it*4 + b] / sc[4 + (it-1)*4 + b];
    const cf* rrow = rres + b*HW + y*WW;
    #pragma unroll
    for (int m = 0; m < 6; ++m) {
      cf rv = rrow[l + 64*m], po = prow[l + 64*m];
      pv[m].x = rv.x + beta*po.x; pv[m].y = rv.y + beta*po.y;
    }
    if (c == 0) {
      cf* pn = pnext + b*HW + y*WW;
      #pragma unroll
      for (int m = 0; m < 6; ++m) pn[l + 64*m] = pv[m];
    }
  }
  const cf* crow = csm + (b*CC + c)*HW + y*WW;
  cf v[6];
  #pragma unroll
  for (int m = 0; m < 6; ++m) v[m] = cmul(crow[l + 64*m], pv[m]);
  cf uA[3], uB[3];
  fft384_wave<-1>(l, v, uA, uB);
  const int R3 = 3 * brev7(l);
  #pragma unroll
  for (int k1 = 0; k1 < 3; ++k1) { rowbuf[wv][padi(k1 + R3)] = uA[k1]; rowbuf[wv][padi(k1 + R3 + 3)] = uB[k1]; }
  __syncthreads();
  cf* trow = t + (b*CC + c)*HW + y*WW;
  #pragma unroll
  for (int m = 0; m < 6; ++m) trow[l + 64*m] = rowbuf[wv][padi(l + 64*m)];
}

__global__ void __launch_bounds__(256) pass_b_k(cf* __restrict__ t, const float* __restrict__ mask) {
  __shared__ cf tile[431*9];
  const int b = blockIdx.z, c = blockIdx.y, x0 = blockIdx.x * 8;
  cf* base = t + (b*CC + c)*HW;
  for (int e = threadIdx.x; e < 3072; e += 256) {
    int y = e >> 3, xx = e & 7;
    tile[padi(y)*9 + xx] = base[y*WW + x0 + xx];
  }
  __syncthreads();
  const int l = threadIdx.x & 63, wv = threadIdx.x >> 6;
  const int R3 = 3 * brev7(l);
  for (int rep = 0; rep < 2; ++rep) {
    const int xx = wv*2 + rep, x = x0 + xx;
    cf v[6];
    #pragma unroll
    for (int m = 0; m < 6; ++m) v[m] = tile[padi(l + 64*m)*9 + xx];
    cf uA[3], uB[3];
    fft384_wave<-1>(l, v, uA, uB);
    const float* mrow = mask + b*HW + x;
    #pragma unroll
    for (int k1 = 0; k1 < 3; ++k1) {
      float mA = mrow[(k1 + R3)*WW], mB = mrow[(k1 + R3 + 3)*WW];
      uA[k1].x *= mA; uA[k1].y *= mA; uB[k1].x *= mB; uB[k1].y *= mB;
    }
    __syncthreads();
    #pragma unroll
    for (int k1 = 0; k1 < 3; ++k1) { tile[padi(k1 + R3)*9 + xx] = uA[k1]; tile[padi(k1 + R3 + 3)*9 + xx] = uB[k1]; }
    __syncthreads();
    #pragma unroll
    for (int m = 0; m < 6; ++m) v[m] = tile[padi(l + 64*m)*9 + xx];
    fft384_wave<1>(l, v, uA, uB);
    const float s = 1.0f / 384.0f;
    #pragma unroll
    for (int k1 = 0; k1 < 3; ++k1) {
      uA[k1].x *= s; uA[k1].y *= s; uB[k1].x *= s; uB[k1].y *= s;
      tile[padi(k1 + R3)*9 + xx] = uA[k1]; tile[padi(k1 + R3 + 3)*9 + xx] = uB[k1];
    }
    __syncthreads();
  }
  for (int e = threadIdx.x; e < 3072; e += 256) {
    int y = e >> 3, xx = e & 7;
    base[y*WW + x0 + xx] = tile[padi(y)*9 + xx];
  }
}

// rows: coil-split (blockIdx.y = half, 4 coils each). half 0 includes lam*p in Ap0.
// Ap = Ap0 + Ap1 (summed in upd1). pAp partials exact per block.
__global__ void __launch_bounds__(256) pass_c_k(const cf* __restrict__ t, const cf* __restrict__ csm,
                                                const cf* __restrict__ p,
                                                cf* __restrict__ Ap0, cf* __restrict__ Ap1,
                                                const float* __restrict__ lam, float* __restrict__ pAp) {
  __shared__ cf rowbuf[4][434];
  __shared__ float wsum[4];
  const int l = threadIdx.x & 63, wv = threadIdx.x >> 6;
  const int y = blockIdx.x * 4 + wv;
  const int half = blockIdx.y, b = blockIdx.z;
  const int R3 = 3 * brev7(l);
  cf acc[6] = {};
  for (int ci = 0; ci < 4; ++ci) {
    const int c = half*4 + ci;
    const cf* trow = t + (b*CC + c)*HW + y*WW;
    cf v[6];
    #pragma unroll
    for (int m = 0; m < 6; ++m) v[m] = trow[l + 64*m];
    cf uA[3], uB[3];
    fft384_wave<1>(l, v, uA, uB);
    __syncthreads();
    #pragma unroll
    for (int k1 = 0; k1 < 3; ++k1) { rowbuf[wv][padi(k1 + R3)] = uA[k1]; rowbuf[wv][padi(k1 + R3 + 3)] = uB[k1]; }
    __syncthreads();
    const cf* crow = csm + (b*CC + c)*HW + y*WW;
    #pragma unroll
    for (int m = 0; m < 6; ++m) {
      cf cs = crow[l + 64*m];
      cf wz = rowbuf[wv][padi(l + 64*m)];
      acc[m].x += cs.x*wz.x + cs.y*wz.y;
      acc[m].y += cs.x*wz.y - cs.y*wz.x;
    }
  }
  const float lamv = (half == 0) ? lam[0] : 0.f;
  const float sc384 = 1.0f / 384.0f;
  const cf* prow = p + b*HW + y*WW;
  cf* aprow = ((half == 0) ? Ap0 : Ap1) + b*HW + y*WW;
  float partial = 0.f;
  #pragma unroll
  for (int m = 0; m < 6; ++m) {
    cf pv = prow[l + 64*m];
    cf ap; ap.x = acc[m].x*sc384 + lamv*pv.x; ap.y = acc[m].y*sc384 + lamv*pv.y;
    aprow[l + 64*m] = ap;
    partial += pv.x*ap.x + pv.y*ap.y;
  }
  for (int off = 32; off; off >>= 1) partial += __shfl_down(partial, off);
  if (l == 0) wsum[wv] = partial;
  __syncthreads();
  if (threadIdx.x == 0) atomicAdd(&pAp[b], wsum[0]+wsum[1]+wsum[2]+wsum[3]);
}

__global__ void __launch_bounds__(256) upd1_k(cf* __restrict__ x, cf* __restrict__ r,
                                              const cf* __restrict__ p,
                                              const cf* __restrict__ Ap0, const cf* __restrict__ Ap1,
                                              const float* __restrict__ rtr_cur,
                                              const float* __restrict__ pAp,
                                              float* __restrict__ rtr_next) {
  __shared__ float wsum[4];
  const int idx = blockIdx.x * 256 + threadIdx.x;
  const int b = idx / HW;
  const float alpha = rtr_cur[b] / pAp[b];
  cf pv = p[idx];
  cf a0 = Ap0[idx], a1 = Ap1[idx];
  cf apv; apv.x = a0.x + a1.x; apv.y = a0.y + a1.y;
  cf xv = x[idx]; xv.x += alpha*pv.x; xv.y += alpha*pv.y; x[idx] = xv;
  cf rv = r[idx]; rv.x -= alpha*apv.x; rv.y -= alpha*apv.y; r[idx] = rv;
  float partial = rv.x*rv.x + rv.y*rv.y;
  for (int off = 32; off; off >>= 1) partial += __shfl_down(partial, off);
  const int l = threadIdx.x & 63, wv = threadIdx.x >> 6;
  if (l == 0) wsum[wv] = partial;
  __syncthreads();
  if (threadIdx.x == 0) atomicAdd(&rtr_next[b], wsum[0]+wsum[1]+wsum[2]+wsum[3]);
}

__global__ void __launch_bounds__(256) store_x_k(const cf* __restrict__ xc, float* __restrict__ out) {
  const int idx = blockIdx.x * 256 + threadIdx.x;
  const int b = idx / HW;
  const int rem = idx - b*HW;
  cf v = xc[idx];
  out[b*2*HW + rem] = v.x;
  out[b*2*HW + HW + rem] = v.y;
}

__global__ void zero_sc_k(float* sc) { if (threadIdx.x < 64) sc[threadIdx.x] = 0.f; }

extern "C" void kernel_launch(void* const* d_in, const int* in_sizes, int n_in,
                              void* d_out, int out_size, void* d_ws, size_t ws_size,
                              hipStream_t stream) {
  (void)in_sizes; (void)n_in; (void)out_size; (void)ws_size;
  const float* under  = (const float*)d_in[0];
  const cf*    csm    = (const cf*)d_in[1];
  const float* mask   = (const float*)d_in[2];
  const float* lam    = (const float*)d_in[3];
  const float* w_in   = (const float*)d_in[4];
  const float* b_in   = (const float*)d_in[5];
  const float* ws_mid = (const float*)d_in[6];
  const float* bs_mid = (const float*)d_in[7];
  const float* w_out  = (const float*)d_in[8];
  const float* b_out  = (const float*)d_in[9];
  float* xcur = (float*)d_out;

  char* bws = (char*)d_ws;
  size_t off = 0;
  auto carve = [&](size_t bytes) { char* pp = bws + off; off += (bytes + 255) & ~(size_t)255; return (void*)pp; };
  __hip_bfloat16* actA = (__hip_bfloat16*)carve((size_t)BB*64*HW*2);
  __hip_bfloat16* actB = (__hip_bfloat16*)carve((size_t)BB*64*HW*2);
  cf* t     = (cf*)carve((size_t)BB*CC*HW*8);
  cf* r     = (cf*)carve((size_t)BB*HW*8);
  cf* pbuf0 = (cf*)carve((size_t)BB*HW*8);
  cf* pbuf1 = (cf*)carve((size_t)BB*HW*8);
  cf* xc    = (cf*)carve((size_t)BB*HW*8);
  cf* Ap0   = (cf*)carve((size_t)BB*HW*8);
  cf* Ap1   = (cf*)carve((size_t)BB*HW*8);
  float* sc = (float*)carve(256*4);
  __hip_bfloat16* wrep = (__hip_bfloat16*)carve((size_t)7*9*64*64*2);

  hipMemcpyAsync(xcur, under, (size_t)BB*2*HW*sizeof(float), hipMemcpyDeviceToDevice, stream);

  repack_mid_k<<<(7*9*64*64 + 255)/256, 256, 0, stream>>>(ws_mid, wrep);

  dim3 cgrid(WW/32, HH/8, BB);
  dim3 agrid(HH/4, CC, BB);
  dim3 cgrid2(HH/4, 2, BB);
  dim3 colgrid(WW/8, CC, BB);
  const int egrid = BB*HW/256;

  __hip_bfloat16* bufs[2] = { actA, actB };
  cf* pbufs[2] = { pbuf0, pbuf1 };

  for (int layer = 0; layer < NLAYERS; ++layer) {
    zero_sc_k<<<1, 64, 0, stream>>>(sc);
    conv_in_k<<<cgrid, 256, 0, stream>>>(xcur, w_in, b_in, bufs[0]);
    for (int i = 0; i < 7; ++i) {
      conv_mid_mfma_k<<<cgrid, 256, 0, stream>>>(bufs[i & 1], wrep + (size_t)i*9*4096,
                                                 bs_mid + i*64, bufs[(i + 1) & 1], (i % 2 == 0) ? 1 : 0);
    }
    conv_out_k<<<cgrid, 256, 0, stream>>>(bufs[1], w_out, b_out, xcur, under, lam,
                                          r, pbuf0, xc, sc + 4);
    for (int it = 0; it < CGITERS; ++it) {
      cf* pprev = (it == 0) ? pbuf0 : pbufs[(it - 1) & 1];
      cf* puse  = pbufs[it & 1];
      pass_a_k<<<agrid, 256, 0, stream>>>(pprev, r, puse, csm, t, sc, it, sc);
      pass_b_k<<<colgrid, 256, 0, stream>>>(t, mask);
      pass_c_k<<<cgrid2, 256, 0, stream>>>(t, csm, puse, Ap0, Ap1, lam, sc);
      upd1_k<<<egrid, 256, 0, stream>>>(xc, r, puse, Ap0, Ap1, sc + 4 + it*4, sc, sc + 4 + (it+1)*4);
    }
    store_x_k<<<egrid, 256, 0, stream>>>(xc, xcur);
  }
}